// Round 2
// baseline (895.727 us; speedup 1.0000x reference)
//
#include <hip/hip_runtime.h>
#include <hip/hip_bf16.h>

// Problem constants (fixed by the reference setup)
#define N_NODES 50000
#define N_EDGES 800000
#define E_TOT   (N_EDGES + N_NODES)   // 850000 (self-loops appended)
#define IN_C    256
#define H1C     256                    // HEADS * HID_C = 4*64
#define HEADS   4
#define HID_C   64
#define OUT_C   128
#define N_GRAPHS 100
#define NEG_SLOPE 0.2f
#define EPS_F 1e-16f

// ---------------------------------------------------------------------------
// CSR build: histogram -> scan -> scatter
// ---------------------------------------------------------------------------
__global__ void hist_kernel(const int* __restrict__ ei, int* __restrict__ hist) {
    int idx = blockIdx.x * 256 + threadIdx.x;
    if (idx < N_EDGES) {
        int d = ei[N_EDGES + idx];                // dst row
        if (d >= 0 && d < N_NODES) atomicAdd(&hist[d], 1);
    } else if (idx < E_TOT) {
        atomicAdd(&hist[idx - N_EDGES], 1);       // self loop
    }
}

__global__ __launch_bounds__(1024) void scan_kernel(const int* __restrict__ hist,
                                                    int* __restrict__ row_ptr,
                                                    int* __restrict__ row_fill) {
    __shared__ int sums[1024];
    const int CH = (N_NODES + 1023) / 1024;       // 49
    int t = threadIdx.x;
    int begin = t * CH;
    int end = begin + CH; if (end > N_NODES) end = N_NODES;
    if (begin > N_NODES) begin = N_NODES;
    int s = 0;
    for (int i = begin; i < end; ++i) s += hist[i];
    sums[t] = s;
    __syncthreads();
    for (int off = 1; off < 1024; off <<= 1) {
        int v = 0;
        if (t >= off) v = sums[t - off];
        __syncthreads();
        sums[t] += v;
        __syncthreads();
    }
    int excl = sums[t] - s;       // exclusive prefix of this chunk
    int run = excl;
    for (int i = begin; i < end; ++i) {
        row_ptr[i] = run;
        row_fill[i] = run;
        run += hist[i];
    }
    if (t == 1023) row_ptr[N_NODES] = run;   // grand total (chunk empty => excl = total)
}

__global__ void scatter_kernel(const int* __restrict__ ei, int* __restrict__ row_fill,
                               int* __restrict__ ssrc) {
    int idx = blockIdx.x * 256 + threadIdx.x;
    if (idx < N_EDGES) {
        int s = ei[idx];
        int d = ei[N_EDGES + idx];
        if (s < 0 || s >= N_NODES || d < 0 || d >= N_NODES) return;  // defensive
        int pos = atomicAdd(&row_fill[d], 1);
        if (pos >= 0 && pos < E_TOT) ssrc[pos] = s;
    } else if (idx < E_TOT) {
        int nd = idx - N_EDGES;
        int pos = atomicAdd(&row_fill[nd], 1);
        if (pos >= 0 && pos < E_TOT) ssrc[pos] = nd;
    }
}

// ---------------------------------------------------------------------------
// SGEMM: C[M,N] = A[M,K] * B[K,N], fp32, 128x128 tile, 8x8 per thread
// ---------------------------------------------------------------------------
__global__ __launch_bounds__(256) void sgemm_kernel(const float* __restrict__ A,
                                                    const float* __restrict__ B,
                                                    float* __restrict__ C,
                                                    int M, int N, int K) {
    __shared__ __align__(16) float As[8][132];
    __shared__ __align__(16) float Bs[8][132];
    const int tid = threadIdx.x;
    const int tileM = blockIdx.x * 128;
    const int tileN = blockIdx.y * 128;
    const int tx = tid & 15, ty = tid >> 4;

    float acc[8][8] = {};

    const int mA = tid >> 1;              // 0..127
    const int kA = (tid & 1) * 4;         // 0 or 4
    const int rowA = tileM + mA;
    const bool rowAok = rowA < M;
    const float* Aptr = A + (size_t)rowA * K + kA;

    const int kB = tid >> 5;              // 0..7
    const int nB = (tid & 31) * 4;        // 0..124
    const float* Bptr = B + (size_t)kB * N + tileN + nB;

    for (int kk = 0; kk < K; kk += 8) {
        float4 av = make_float4(0.f, 0.f, 0.f, 0.f);
        if (rowAok) av = *reinterpret_cast<const float4*>(Aptr + kk);
        float4 bv = *reinterpret_cast<const float4*>(Bptr + (size_t)kk * N);
        __syncthreads();
        As[kA + 0][mA] = av.x;
        As[kA + 1][mA] = av.y;
        As[kA + 2][mA] = av.z;
        As[kA + 3][mA] = av.w;
        *reinterpret_cast<float4*>(&Bs[kB][nB]) = bv;
        __syncthreads();
#pragma unroll
        for (int k = 0; k < 8; ++k) {
            float4 a0 = *reinterpret_cast<const float4*>(&As[k][ty * 8]);
            float4 a1 = *reinterpret_cast<const float4*>(&As[k][ty * 8 + 4]);
            float4 b0 = *reinterpret_cast<const float4*>(&Bs[k][tx * 8]);
            float4 b1 = *reinterpret_cast<const float4*>(&Bs[k][tx * 8 + 4]);
            float a[8] = {a0.x, a0.y, a0.z, a0.w, a1.x, a1.y, a1.z, a1.w};
            float b[8] = {b0.x, b0.y, b0.z, b0.w, b1.x, b1.y, b1.z, b1.w};
#pragma unroll
            for (int i = 0; i < 8; ++i)
#pragma unroll
                for (int j = 0; j < 8; ++j)
                    acc[i][j] += a[i] * b[j];
        }
    }
#pragma unroll
    for (int i = 0; i < 8; ++i) {
        int row = tileM + ty * 8 + i;
        if (row < M) {
            float4 c0 = make_float4(acc[i][0], acc[i][1], acc[i][2], acc[i][3]);
            float4 c1 = make_float4(acc[i][4], acc[i][5], acc[i][6], acc[i][7]);
            float* cp = C + (size_t)row * N + tileN + tx * 8;
            *reinterpret_cast<float4*>(cp) = c0;
            *reinterpret_cast<float4*>(cp + 4) = c1;
        }
    }
}

// ---------------------------------------------------------------------------
// Attention score dots
// ---------------------------------------------------------------------------
__global__ __launch_bounds__(256) void att1_kernel(const float* __restrict__ h1,
                                                   const float* __restrict__ att_src,
                                                   const float* __restrict__ att_dst,
                                                   float* __restrict__ a_src_o,
                                                   float* __restrict__ a_dst_o) {
    int node = blockIdx.x * 4 + (threadIdx.x >> 6);
    int lane = threadIdx.x & 63;
    float4 hv = reinterpret_cast<const float4*>(h1)[(size_t)node * 64 + lane];
    float4 as = reinterpret_cast<const float4*>(att_src)[lane];
    float4 ad = reinterpret_cast<const float4*>(att_dst)[lane];
    float ps = hv.x * as.x + hv.y * as.y + hv.z * as.z + hv.w * as.w;
    float pd = hv.x * ad.x + hv.y * ad.y + hv.z * ad.z + hv.w * ad.w;
#pragma unroll
    for (int off = 1; off < 16; off <<= 1) {
        ps += __shfl_xor(ps, off);
        pd += __shfl_xor(pd, off);
    }
    if ((lane & 15) == 0) {
        int hd = lane >> 4;
        a_src_o[node * 4 + hd] = ps;
        a_dst_o[node * 4 + hd] = pd;
    }
}

__global__ __launch_bounds__(256) void att2_kernel(const float* __restrict__ h2,
                                                   const float* __restrict__ att_src,
                                                   const float* __restrict__ att_dst,
                                                   float* __restrict__ a_src_o,
                                                   float* __restrict__ a_dst_o) {
    int node = blockIdx.x * 4 + (threadIdx.x >> 6);
    int lane = threadIdx.x & 63;
    float2 hv = reinterpret_cast<const float2*>(h2)[(size_t)node * 64 + lane];
    float2 as = reinterpret_cast<const float2*>(att_src)[lane];
    float2 ad = reinterpret_cast<const float2*>(att_dst)[lane];
    float ps = hv.x * as.x + hv.y * as.y;
    float pd = hv.x * ad.x + hv.y * ad.y;
#pragma unroll
    for (int off = 1; off < 64; off <<= 1) {
        ps += __shfl_xor(ps, off);
        pd += __shfl_xor(pd, off);
    }
    if (lane == 0) {
        a_src_o[node] = ps;
        a_dst_o[node] = pd;
    }
}

__device__ __forceinline__ float lrelu(float x) { return x > 0.f ? x : NEG_SLOPE * x; }

// ---------------------------------------------------------------------------
// Edge aggregation, layer 1: one wave per destination node, 4 heads x 64 ch
// ---------------------------------------------------------------------------
__global__ __launch_bounds__(256) void edge1_kernel(const int* __restrict__ row_ptr,
                                                    const int* __restrict__ ssrc,
                                                    const float* __restrict__ h1,
                                                    const float* __restrict__ a_src,
                                                    const float* __restrict__ a_dst,
                                                    const float* __restrict__ bias,
                                                    float* __restrict__ out) {
    int node = blockIdx.x * 4 + (threadIdx.x >> 6);
    int lane = threadIdx.x & 63;
    int start = row_ptr[node], end = row_ptr[node + 1];
    float ad0 = a_dst[node * 4 + 0];
    float ad1 = a_dst[node * 4 + 1];
    float ad2 = a_dst[node * 4 + 2];
    float ad3 = a_dst[node * 4 + 3];

    // Phase A: softmax denominator per head (max-shift skipped: alphas are O(1))
    float s0 = 0.f, s1 = 0.f, s2 = 0.f, s3 = 0.f;
    for (int e = start + lane; e < end; e += 64) {
        int si = ssrc[e];
        float4 av = reinterpret_cast<const float4*>(a_src)[si];
        s0 += __expf(lrelu(av.x + ad0));
        s1 += __expf(lrelu(av.y + ad1));
        s2 += __expf(lrelu(av.z + ad2));
        s3 += __expf(lrelu(av.w + ad3));
    }
#pragma unroll
    for (int off = 1; off < 64; off <<= 1) {
        s0 += __shfl_xor(s0, off);
        s1 += __shfl_xor(s1, off);
        s2 += __shfl_xor(s2, off);
        s3 += __shfl_xor(s3, off);
    }
    int hd = lane >> 4;
    float Ssel = hd == 0 ? s0 : hd == 1 ? s1 : hd == 2 ? s2 : s3;
    float adh  = hd == 0 ? ad0 : hd == 1 ? ad1 : hd == 2 ? ad2 : ad3;
    float inv = 1.0f / (Ssel + EPS_F);

    // Phase B: weighted gather-accumulate; lane holds flat channels lane*4..+3
    float4 acc = make_float4(0.f, 0.f, 0.f, 0.f);
    for (int e = start; e < end; ++e) {
        int si = ssrc[e];
        float w = __expf(lrelu(a_src[si * 4 + hd] + adh)) * inv;
        float4 hv = reinterpret_cast<const float4*>(h1)[(size_t)si * 64 + lane];
        acc.x += w * hv.x;
        acc.y += w * hv.y;
        acc.z += w * hv.z;
        acc.w += w * hv.w;
    }
    float4 bv = reinterpret_cast<const float4*>(bias)[lane];
    acc.x = fmaxf(acc.x + bv.x, 0.f);
    acc.y = fmaxf(acc.y + bv.y, 0.f);
    acc.z = fmaxf(acc.z + bv.z, 0.f);
    acc.w = fmaxf(acc.w + bv.w, 0.f);
    reinterpret_cast<float4*>(out)[(size_t)node * 64 + lane] = acc;
}

// ---------------------------------------------------------------------------
// Edge aggregation, layer 2: one wave per destination node, 1 head x 128 ch
// ---------------------------------------------------------------------------
__global__ __launch_bounds__(256) void edge2_kernel(const int* __restrict__ row_ptr,
                                                    const int* __restrict__ ssrc,
                                                    const float* __restrict__ h2,
                                                    const float* __restrict__ a_src,
                                                    const float* __restrict__ a_dst,
                                                    const float* __restrict__ bias,
                                                    float* __restrict__ out) {
    int node = blockIdx.x * 4 + (threadIdx.x >> 6);
    int lane = threadIdx.x & 63;
    int start = row_ptr[node], end = row_ptr[node + 1];
    float ad = a_dst[node];

    float s = 0.f;
    for (int e = start + lane; e < end; e += 64) {
        int si = ssrc[e];
        s += __expf(lrelu(a_src[si] + ad));
    }
#pragma unroll
    for (int off = 1; off < 64; off <<= 1) s += __shfl_xor(s, off);
    float inv = 1.0f / (s + EPS_F);

    float2 acc = make_float2(0.f, 0.f);
    for (int e = start; e < end; ++e) {
        int si = ssrc[e];
        float w = __expf(lrelu(a_src[si] + ad)) * inv;
        float2 hv = reinterpret_cast<const float2*>(h2)[(size_t)si * 64 + lane];
        acc.x += w * hv.x;
        acc.y += w * hv.y;
    }
    float2 bv = reinterpret_cast<const float2*>(bias)[lane];
    acc.x = fmaxf(acc.x + bv.x, 0.f);
    acc.y = fmaxf(acc.y + bv.y, 0.f);
    reinterpret_cast<float2*>(out)[(size_t)node * 64 + lane] = acc;
}

// ---------------------------------------------------------------------------
// Pooling: batch is sorted -> per-block running accumulator, flush on change
// ---------------------------------------------------------------------------
__global__ __launch_bounds__(128) void pool_kernel(const float* __restrict__ out2,
                                                   const int* __restrict__ batch,
                                                   float* __restrict__ d_out) {
    int c = threadIdx.x;                 // channel 0..127
    int node0 = blockIdx.x * 128;
    int nodeEnd = node0 + 128; if (nodeEnd > N_NODES) nodeEnd = N_NODES;
    if (node0 >= N_NODES) return;
    int gprev = batch[node0];
    float acc = 0.f;
    for (int node = node0; node < nodeEnd; ++node) {
        int g = batch[node];
        if (g != gprev) {
            if (gprev >= 0 && gprev < N_GRAPHS) atomicAdd(&d_out[gprev * 128 + c], acc);
            acc = 0.f;
            gprev = g;
        }
        acc += out2[(size_t)node * 128 + c];
    }
    if (gprev >= 0 && gprev < N_GRAPHS) atomicAdd(&d_out[gprev * 128 + c], acc);
}

__global__ void count_kernel(const int* __restrict__ batch, int* __restrict__ cnt) {
    int idx = blockIdx.x * 256 + threadIdx.x;
    if (idx < N_NODES) {
        int g = batch[idx];
        if (g >= 0 && g < N_GRAPHS) atomicAdd(&cnt[g], 1);
    }
}

__global__ void final_kernel(float* __restrict__ d_out, const int* __restrict__ cnt) {
    int idx = blockIdx.x * 256 + threadIdx.x;
    if (idx < N_GRAPHS * 128) {
        int g = idx >> 7;
        float c = (float)cnt[g];
        if (c < 1.f) c = 1.f;
        d_out[idx] = d_out[idx] / c;
    }
}

// ---------------------------------------------------------------------------
extern "C" void kernel_launch(void* const* d_in, const int* in_sizes, int n_in,
                              void* d_out_v, int out_size, void* d_ws, size_t ws_size,
                              hipStream_t stream) {
    const float* x      = (const float*)d_in[0];
    const float* W1     = (const float*)d_in[1];
    const float* att_s1 = (const float*)d_in[2];
    const float* att_d1 = (const float*)d_in[3];
    const float* bias1  = (const float*)d_in[4];
    const float* W2     = (const float*)d_in[5];
    const float* att_s2 = (const float*)d_in[6];
    const float* att_d2 = (const float*)d_in[7];
    const float* bias2  = (const float*)d_in[8];
    const int*   ei     = (const int*)d_in[9];
    const int*   batch  = (const int*)d_in[10];
    float* d_out = (float*)d_out_v;

    // Workspace layout (floats)
    float* ws = (float*)d_ws;
    float* h1     = ws;                        // 12,800,000 (N*256)  [reused: h2 + out2]
    float* out1   = h1 + 12800000;             // 12,800,000
    float* h2     = h1;                        // N*128 = 6,400,000 (h1 dead by then)
    float* out2   = h1 + 6400000;              // N*128 = 6,400,000
    float* a_src1 = out1 + 12800000;           // N*4
    float* a_dst1 = a_src1 + 200000;           // N*4
    float* a_src2 = a_dst1 + 200000;           // N
    float* a_dst2 = a_src2 + 50000;            // N
    int* hist     = (int*)(a_dst2 + 50000);    // N
    int* row_ptr  = hist + 50000;              // N+1 (padded to 50016)
    int* row_fill = row_ptr + 50016;           // N (padded to 50016)
    int* ssrc     = row_fill + 50016;          // E_TOT
    int* cnt      = ssrc + E_TOT;              // N_GRAPHS

    // Zero what must be zero
    hipMemsetAsync(hist, 0, N_NODES * sizeof(int), stream);
    hipMemsetAsync(cnt, 0, N_GRAPHS * sizeof(int), stream);
    hipMemsetAsync(d_out, 0, N_GRAPHS * 128 * sizeof(float), stream);

    // CSR build
    hist_kernel<<<(E_TOT + 255) / 256, 256, 0, stream>>>(ei, hist);
    scan_kernel<<<1, 1024, 0, stream>>>(hist, row_ptr, row_fill);
    scatter_kernel<<<(E_TOT + 255) / 256, 256, 0, stream>>>(ei, row_fill, ssrc);

    // Layer 1
    {
        dim3 g((N_NODES + 127) / 128, H1C / 128);
        sgemm_kernel<<<g, 256, 0, stream>>>(x, W1, h1, N_NODES, H1C, IN_C);
    }
    att1_kernel<<<N_NODES / 4, 256, 0, stream>>>(h1, att_s1, att_d1, a_src1, a_dst1);
    edge1_kernel<<<N_NODES / 4, 256, 0, stream>>>(row_ptr, ssrc, h1, a_src1, a_dst1, bias1, out1);

    // Layer 2
    {
        dim3 g((N_NODES + 127) / 128, OUT_C / 128);
        sgemm_kernel<<<g, 256, 0, stream>>>(out1, W2, h2, N_NODES, OUT_C, H1C);
    }
    att2_kernel<<<N_NODES / 4, 256, 0, stream>>>(h2, att_s2, att_d2, a_src2, a_dst2);
    edge2_kernel<<<N_NODES / 4, 256, 0, stream>>>(row_ptr, ssrc, h2, a_src2, a_dst2, bias2, out2);

    // Pooling
    count_kernel<<<(N_NODES + 255) / 256, 256, 0, stream>>>(batch, cnt);
    pool_kernel<<<(N_NODES + 127) / 128, 128, 0, stream>>>(out2, batch, d_out);
    final_kernel<<<(N_GRAPHS * 128 + 255) / 256, 256, 0, stream>>>(d_out, cnt);
}

// Round 3
// 744.213 us; speedup vs baseline: 1.2036x; 1.2036x over previous
//
#include <hip/hip_runtime.h>
#include <hip/hip_bf16.h>

// Problem constants (fixed by the reference setup)
#define N_NODES 50000
#define N_EDGES 800000
#define E_TOT   (N_EDGES + N_NODES)   // 850000 (self-loops appended)
#define IN_C    256
#define H1C     256                    // HEADS * HID_C = 4*64
#define HEADS   4
#define HID_C   64
#define OUT_C   128
#define N_GRAPHS 100
#define NEG_SLOPE 0.2f
#define EPS_F 1e-16f

// ---------------------------------------------------------------------------
// CSR build: histogram -> scan -> scatter
// ---------------------------------------------------------------------------
__global__ void hist_kernel(const int* __restrict__ ei, int* __restrict__ hist) {
    int idx = blockIdx.x * 256 + threadIdx.x;
    if (idx < N_EDGES) {
        int d = ei[N_EDGES + idx];                // dst row
        if (d >= 0 && d < N_NODES) atomicAdd(&hist[d], 1);
    } else if (idx < E_TOT) {
        atomicAdd(&hist[idx - N_EDGES], 1);       // self loop
    }
}

__global__ __launch_bounds__(1024) void scan_kernel(const int* __restrict__ hist,
                                                    int* __restrict__ row_ptr,
                                                    int* __restrict__ row_fill) {
    __shared__ int sums[1024];
    const int CH = (N_NODES + 1023) / 1024;       // 49
    int t = threadIdx.x;
    int begin = t * CH;
    int end = begin + CH; if (end > N_NODES) end = N_NODES;
    if (begin > N_NODES) begin = N_NODES;
    int s = 0;
    for (int i = begin; i < end; ++i) s += hist[i];
    sums[t] = s;
    __syncthreads();
    for (int off = 1; off < 1024; off <<= 1) {
        int v = 0;
        if (t >= off) v = sums[t - off];
        __syncthreads();
        sums[t] += v;
        __syncthreads();
    }
    int excl = sums[t] - s;       // exclusive prefix of this chunk
    int run = excl;
    for (int i = begin; i < end; ++i) {
        row_ptr[i] = run;
        row_fill[i] = run;
        run += hist[i];
    }
    if (t == 1023) row_ptr[N_NODES] = run;   // grand total (chunk empty => excl = total)
}

__global__ void scatter_kernel(const int* __restrict__ ei, int* __restrict__ row_fill,
                               int* __restrict__ ssrc) {
    int idx = blockIdx.x * 256 + threadIdx.x;
    if (idx < N_EDGES) {
        int s = ei[idx];
        int d = ei[N_EDGES + idx];
        if (s < 0 || s >= N_NODES || d < 0 || d >= N_NODES) return;  // defensive
        int pos = atomicAdd(&row_fill[d], 1);
        if (pos >= 0 && pos < E_TOT) ssrc[pos] = s;
    } else if (idx < E_TOT) {
        int nd = idx - N_EDGES;
        int pos = atomicAdd(&row_fill[nd], 1);
        if (pos >= 0 && pos < E_TOT) ssrc[pos] = nd;
    }
}

// ---------------------------------------------------------------------------
// SGEMM: C[M,N] = A[M,K] * B[K,N], fp32, 128x128 tile, 8x8 per thread
// ---------------------------------------------------------------------------
__global__ __launch_bounds__(256) void sgemm_kernel(const float* __restrict__ A,
                                                    const float* __restrict__ B,
                                                    float* __restrict__ C,
                                                    int M, int N, int K) {
    __shared__ __align__(16) float As[8][132];
    __shared__ __align__(16) float Bs[8][132];
    const int tid = threadIdx.x;
    const int tileM = blockIdx.x * 128;
    const int tileN = blockIdx.y * 128;
    const int tx = tid & 15, ty = tid >> 4;

    float acc[8][8] = {};

    const int mA = tid >> 1;              // 0..127
    const int kA = (tid & 1) * 4;         // 0 or 4
    const int rowA = tileM + mA;
    const bool rowAok = rowA < M;
    const float* Aptr = A + (size_t)rowA * K + kA;

    const int kB = tid >> 5;              // 0..7
    const int nB = (tid & 31) * 4;        // 0..124
    const float* Bptr = B + (size_t)kB * N + tileN + nB;

    for (int kk = 0; kk < K; kk += 8) {
        float4 av = make_float4(0.f, 0.f, 0.f, 0.f);
        if (rowAok) av = *reinterpret_cast<const float4*>(Aptr + kk);
        float4 bv = *reinterpret_cast<const float4*>(Bptr + (size_t)kk * N);
        __syncthreads();
        As[kA + 0][mA] = av.x;
        As[kA + 1][mA] = av.y;
        As[kA + 2][mA] = av.z;
        As[kA + 3][mA] = av.w;
        *reinterpret_cast<float4*>(&Bs[kB][nB]) = bv;
        __syncthreads();
#pragma unroll
        for (int k = 0; k < 8; ++k) {
            float4 a0 = *reinterpret_cast<const float4*>(&As[k][ty * 8]);
            float4 a1 = *reinterpret_cast<const float4*>(&As[k][ty * 8 + 4]);
            float4 b0 = *reinterpret_cast<const float4*>(&Bs[k][tx * 8]);
            float4 b1 = *reinterpret_cast<const float4*>(&Bs[k][tx * 8 + 4]);
            float a[8] = {a0.x, a0.y, a0.z, a0.w, a1.x, a1.y, a1.z, a1.w};
            float b[8] = {b0.x, b0.y, b0.z, b0.w, b1.x, b1.y, b1.z, b1.w};
#pragma unroll
            for (int i = 0; i < 8; ++i)
#pragma unroll
                for (int j = 0; j < 8; ++j)
                    acc[i][j] += a[i] * b[j];
        }
    }
#pragma unroll
    for (int i = 0; i < 8; ++i) {
        int row = tileM + ty * 8 + i;
        if (row < M) {
            float4 c0 = make_float4(acc[i][0], acc[i][1], acc[i][2], acc[i][3]);
            float4 c1 = make_float4(acc[i][4], acc[i][5], acc[i][6], acc[i][7]);
            float* cp = C + (size_t)row * N + tileN + tx * 8;
            *reinterpret_cast<float4*>(cp) = c0;
            *reinterpret_cast<float4*>(cp + 4) = c1;
        }
    }
}

// ---------------------------------------------------------------------------
// Attention score dots
// ---------------------------------------------------------------------------
__global__ __launch_bounds__(256) void att1_kernel(const float* __restrict__ h1,
                                                   const float* __restrict__ att_src,
                                                   const float* __restrict__ att_dst,
                                                   float* __restrict__ a_src_o,
                                                   float* __restrict__ a_dst_o) {
    int node = blockIdx.x * 4 + (threadIdx.x >> 6);
    int lane = threadIdx.x & 63;
    float4 hv = reinterpret_cast<const float4*>(h1)[(size_t)node * 64 + lane];
    float4 as = reinterpret_cast<const float4*>(att_src)[lane];
    float4 ad = reinterpret_cast<const float4*>(att_dst)[lane];
    float ps = hv.x * as.x + hv.y * as.y + hv.z * as.z + hv.w * as.w;
    float pd = hv.x * ad.x + hv.y * ad.y + hv.z * ad.z + hv.w * ad.w;
#pragma unroll
    for (int off = 1; off < 16; off <<= 1) {
        ps += __shfl_xor(ps, off);
        pd += __shfl_xor(pd, off);
    }
    if ((lane & 15) == 0) {
        int hd = lane >> 4;
        a_src_o[node * 4 + hd] = ps;
        a_dst_o[node * 4 + hd] = pd;
    }
}

__global__ __launch_bounds__(256) void att2_kernel(const float* __restrict__ h2,
                                                   const float* __restrict__ att_src,
                                                   const float* __restrict__ att_dst,
                                                   float* __restrict__ a_src_o,
                                                   float* __restrict__ a_dst_o) {
    int node = blockIdx.x * 4 + (threadIdx.x >> 6);
    int lane = threadIdx.x & 63;
    float2 hv = reinterpret_cast<const float2*>(h2)[(size_t)node * 64 + lane];
    float2 as = reinterpret_cast<const float2*>(att_src)[lane];
    float2 ad = reinterpret_cast<const float2*>(att_dst)[lane];
    float ps = hv.x * as.x + hv.y * as.y;
    float pd = hv.x * ad.x + hv.y * ad.y;
#pragma unroll
    for (int off = 1; off < 64; off <<= 1) {
        ps += __shfl_xor(ps, off);
        pd += __shfl_xor(pd, off);
    }
    if (lane == 0) {
        a_src_o[node] = ps;
        a_dst_o[node] = pd;
    }
}

__device__ __forceinline__ float lrelu(float x) { return x > 0.f ? x : NEG_SLOPE * x; }

// ---------------------------------------------------------------------------
// Edge aggregation, layer 1: one wave per destination node, 4 heads x 64 ch
// ---------------------------------------------------------------------------
__global__ __launch_bounds__(256) void edge1_kernel(const int* __restrict__ row_ptr,
                                                    const int* __restrict__ ssrc,
                                                    const float* __restrict__ h1,
                                                    const float* __restrict__ a_src,
                                                    const float* __restrict__ a_dst,
                                                    const float* __restrict__ bias,
                                                    float* __restrict__ out) {
    int node = blockIdx.x * 4 + (threadIdx.x >> 6);
    int lane = threadIdx.x & 63;
    int start = row_ptr[node], end = row_ptr[node + 1];
    float ad0 = a_dst[node * 4 + 0];
    float ad1 = a_dst[node * 4 + 1];
    float ad2 = a_dst[node * 4 + 2];
    float ad3 = a_dst[node * 4 + 3];

    // Phase A: softmax denominator per head (max-shift skipped: alphas are O(1))
    float s0 = 0.f, s1 = 0.f, s2 = 0.f, s3 = 0.f;
    for (int e = start + lane; e < end; e += 64) {
        int si = ssrc[e];
        float4 av = reinterpret_cast<const float4*>(a_src)[si];
        s0 += __expf(lrelu(av.x + ad0));
        s1 += __expf(lrelu(av.y + ad1));
        s2 += __expf(lrelu(av.z + ad2));
        s3 += __expf(lrelu(av.w + ad3));
    }
#pragma unroll
    for (int off = 1; off < 64; off <<= 1) {
        s0 += __shfl_xor(s0, off);
        s1 += __shfl_xor(s1, off);
        s2 += __shfl_xor(s2, off);
        s3 += __shfl_xor(s3, off);
    }
    int hd = lane >> 4;
    float Ssel = hd == 0 ? s0 : hd == 1 ? s1 : hd == 2 ? s2 : s3;
    float adh  = hd == 0 ? ad0 : hd == 1 ? ad1 : hd == 2 ? ad2 : ad3;
    float inv = 1.0f / (Ssel + EPS_F);

    // Phase B: weighted gather-accumulate; lane holds flat channels lane*4..+3
    float4 acc = make_float4(0.f, 0.f, 0.f, 0.f);
    for (int e = start; e < end; ++e) {
        int si = ssrc[e];
        float w = __expf(lrelu(a_src[si * 4 + hd] + adh)) * inv;
        float4 hv = reinterpret_cast<const float4*>(h1)[(size_t)si * 64 + lane];
        acc.x += w * hv.x;
        acc.y += w * hv.y;
        acc.z += w * hv.z;
        acc.w += w * hv.w;
    }
    float4 bv = reinterpret_cast<const float4*>(bias)[lane];
    acc.x = fmaxf(acc.x + bv.x, 0.f);
    acc.y = fmaxf(acc.y + bv.y, 0.f);
    acc.z = fmaxf(acc.z + bv.z, 0.f);
    acc.w = fmaxf(acc.w + bv.w, 0.f);
    reinterpret_cast<float4*>(out)[(size_t)node * 64 + lane] = acc;
}

// ---------------------------------------------------------------------------
// Edge aggregation, layer 2: one wave per destination node, 1 head x 128 ch
// ---------------------------------------------------------------------------
__global__ __launch_bounds__(256) void edge2_kernel(const int* __restrict__ row_ptr,
                                                    const int* __restrict__ ssrc,
                                                    const float* __restrict__ h2,
                                                    const float* __restrict__ a_src,
                                                    const float* __restrict__ a_dst,
                                                    const float* __restrict__ bias,
                                                    float* __restrict__ out) {
    int node = blockIdx.x * 4 + (threadIdx.x >> 6);
    int lane = threadIdx.x & 63;
    int start = row_ptr[node], end = row_ptr[node + 1];
    float ad = a_dst[node];

    float s = 0.f;
    for (int e = start + lane; e < end; e += 64) {
        int si = ssrc[e];
        s += __expf(lrelu(a_src[si] + ad));
    }
#pragma unroll
    for (int off = 1; off < 64; off <<= 1) s += __shfl_xor(s, off);
    float inv = 1.0f / (s + EPS_F);

    float2 acc = make_float2(0.f, 0.f);
    for (int e = start; e < end; ++e) {
        int si = ssrc[e];
        float w = __expf(lrelu(a_src[si] + ad)) * inv;
        float2 hv = reinterpret_cast<const float2*>(h2)[(size_t)si * 64 + lane];
        acc.x += w * hv.x;
        acc.y += w * hv.y;
    }
    float2 bv = reinterpret_cast<const float2*>(bias)[lane];
    acc.x = fmaxf(acc.x + bv.x, 0.f);
    acc.y = fmaxf(acc.y + bv.y, 0.f);
    reinterpret_cast<float2*>(out)[(size_t)node * 64 + lane] = acc;
}

// ---------------------------------------------------------------------------
// Pooling: batch is sorted -> per-block running accumulator, flush on change
// ---------------------------------------------------------------------------
__global__ __launch_bounds__(128) void pool_kernel(const float* __restrict__ out2,
                                                   const int* __restrict__ batch,
                                                   float* __restrict__ d_out) {
    int c = threadIdx.x;                 // channel 0..127
    int node0 = blockIdx.x * 128;
    int nodeEnd = node0 + 128; if (nodeEnd > N_NODES) nodeEnd = N_NODES;
    if (node0 >= N_NODES) return;
    int gprev = batch[node0];
    float acc = 0.f;
    for (int node = node0; node < nodeEnd; ++node) {
        int g = batch[node];
        if (g != gprev) {
            if (gprev >= 0 && gprev < N_GRAPHS) atomicAdd(&d_out[gprev * 128 + c], acc);
            acc = 0.f;
            gprev = g;
        }
        acc += out2[(size_t)node * 128 + c];
    }
    if (gprev >= 0 && gprev < N_GRAPHS) atomicAdd(&d_out[gprev * 128 + c], acc);
}

// Graph boundary detection: batch is sorted, so each graph's start index is
// written exactly once (no contended atomics — replaces count_kernel's 50000
// same-address atomicAdds that cost 151 us).
__global__ void bounds_kernel(const int* __restrict__ batch, int* __restrict__ gstart) {
    int idx = blockIdx.x * 256 + threadIdx.x;
    if (idx >= N_NODES) return;
    int g = batch[idx];
    if (g < 0) g = 0; if (g >= N_GRAPHS) g = N_GRAPHS - 1;
    if (idx == 0) {
        for (int j = 0; j <= g; ++j) gstart[j] = 0;
    } else {
        int gp = batch[idx - 1];
        if (gp < 0) gp = 0; if (gp >= N_GRAPHS) gp = N_GRAPHS - 1;
        for (int j = gp + 1; j <= g; ++j) gstart[j] = idx;
    }
    if (idx == N_NODES - 1) {
        for (int j = g + 1; j <= N_GRAPHS; ++j) gstart[j] = N_NODES;
    }
}

__global__ void final_kernel(float* __restrict__ d_out, const int* __restrict__ gstart) {
    int idx = blockIdx.x * 256 + threadIdx.x;
    if (idx < N_GRAPHS * 128) {
        int g = idx >> 7;
        float c = (float)(gstart[g + 1] - gstart[g]);
        if (c < 1.f) c = 1.f;
        d_out[idx] = d_out[idx] / c;
    }
}

// ---------------------------------------------------------------------------
extern "C" void kernel_launch(void* const* d_in, const int* in_sizes, int n_in,
                              void* d_out_v, int out_size, void* d_ws, size_t ws_size,
                              hipStream_t stream) {
    const float* x      = (const float*)d_in[0];
    const float* W1     = (const float*)d_in[1];
    const float* att_s1 = (const float*)d_in[2];
    const float* att_d1 = (const float*)d_in[3];
    const float* bias1  = (const float*)d_in[4];
    const float* W2     = (const float*)d_in[5];
    const float* att_s2 = (const float*)d_in[6];
    const float* att_d2 = (const float*)d_in[7];
    const float* bias2  = (const float*)d_in[8];
    const int*   ei     = (const int*)d_in[9];
    const int*   batch  = (const int*)d_in[10];
    float* d_out = (float*)d_out_v;

    // Workspace layout (floats)
    float* ws = (float*)d_ws;
    float* h1     = ws;                        // 12,800,000 (N*256)  [reused: h2 + out2]
    float* out1   = h1 + 12800000;             // 12,800,000
    float* h2     = h1;                        // N*128 = 6,400,000 (h1 dead by then)
    float* out2   = h1 + 6400000;              // N*128 = 6,400,000
    float* a_src1 = out1 + 12800000;           // N*4
    float* a_dst1 = a_src1 + 200000;           // N*4
    float* a_src2 = a_dst1 + 200000;           // N
    float* a_dst2 = a_src2 + 50000;            // N
    int* hist     = (int*)(a_dst2 + 50000);    // N
    int* row_ptr  = hist + 50000;              // N+1 (padded to 50016)
    int* row_fill = row_ptr + 50016;           // N (padded to 50016)
    int* ssrc     = row_fill + 50016;          // E_TOT
    int* gstart   = ssrc + E_TOT;              // N_GRAPHS+1

    // Zero what must be zero
    hipMemsetAsync(hist, 0, N_NODES * sizeof(int), stream);
    hipMemsetAsync(d_out, 0, N_GRAPHS * 128 * sizeof(float), stream);

    // CSR build
    hist_kernel<<<(E_TOT + 255) / 256, 256, 0, stream>>>(ei, hist);
    scan_kernel<<<1, 1024, 0, stream>>>(hist, row_ptr, row_fill);
    scatter_kernel<<<(E_TOT + 255) / 256, 256, 0, stream>>>(ei, row_fill, ssrc);
    bounds_kernel<<<(N_NODES + 255) / 256, 256, 0, stream>>>(batch, gstart);

    // Layer 1
    {
        dim3 g((N_NODES + 127) / 128, H1C / 128);
        sgemm_kernel<<<g, 256, 0, stream>>>(x, W1, h1, N_NODES, H1C, IN_C);
    }
    att1_kernel<<<N_NODES / 4, 256, 0, stream>>>(h1, att_s1, att_d1, a_src1, a_dst1);
    edge1_kernel<<<N_NODES / 4, 256, 0, stream>>>(row_ptr, ssrc, h1, a_src1, a_dst1, bias1, out1);

    // Layer 2
    {
        dim3 g((N_NODES + 127) / 128, OUT_C / 128);
        sgemm_kernel<<<g, 256, 0, stream>>>(out1, W2, h2, N_NODES, OUT_C, H1C);
    }
    att2_kernel<<<N_NODES / 4, 256, 0, stream>>>(h2, att_s2, att_d2, a_src2, a_dst2);
    edge2_kernel<<<N_NODES / 4, 256, 0, stream>>>(row_ptr, ssrc, h2, a_src2, a_dst2, bias2, out2);

    // Pooling
    pool_kernel<<<(N_NODES + 127) / 128, 128, 0, stream>>>(out2, batch, d_out);
    final_kernel<<<(N_GRAPHS * 128 + 255) / 256, 256, 0, stream>>>(d_out, gstart);
}

// Round 4
// 700.876 us; speedup vs baseline: 1.2780x; 1.0618x over previous
//
#include <hip/hip_runtime.h>
#include <hip/hip_bf16.h>

// Problem constants (fixed by the reference setup)
#define N_NODES 50000
#define N_EDGES 800000
#define E_TOT   (N_EDGES + N_NODES)   // 850000 (self-loops appended)
#define IN_C    256
#define H1C     256                    // HEADS * HID_C = 4*64
#define HEADS   4
#define HID_C   64
#define OUT_C   128
#define N_GRAPHS 100
#define NEG_SLOPE 0.2f
#define EPS_F 1e-16f

// ---------------------------------------------------------------------------
// CSR build: histogram -> scan -> scatter
// ---------------------------------------------------------------------------
__global__ void hist_kernel(const int* __restrict__ ei, int* __restrict__ hist) {
    int idx = blockIdx.x * 256 + threadIdx.x;
    if (idx < N_EDGES) {
        int d = ei[N_EDGES + idx];                // dst row
        if (d >= 0 && d < N_NODES) atomicAdd(&hist[d], 1);
    } else if (idx < E_TOT) {
        atomicAdd(&hist[idx - N_EDGES], 1);       // self loop
    }
}

__global__ __launch_bounds__(1024) void scan_kernel(const int* __restrict__ hist,
                                                    int* __restrict__ row_ptr,
                                                    int* __restrict__ row_fill) {
    __shared__ int sums[1024];
    const int CH = (N_NODES + 1023) / 1024;       // 49
    int t = threadIdx.x;
    int begin = t * CH;
    int end = begin + CH; if (end > N_NODES) end = N_NODES;
    if (begin > N_NODES) begin = N_NODES;
    int s = 0;
    for (int i = begin; i < end; ++i) s += hist[i];
    sums[t] = s;
    __syncthreads();
    for (int off = 1; off < 1024; off <<= 1) {
        int v = 0;
        if (t >= off) v = sums[t - off];
        __syncthreads();
        sums[t] += v;
        __syncthreads();
    }
    int excl = sums[t] - s;       // exclusive prefix of this chunk
    int run = excl;
    for (int i = begin; i < end; ++i) {
        row_ptr[i] = run;
        row_fill[i] = run;
        run += hist[i];
    }
    if (t == 1023) row_ptr[N_NODES] = run;   // grand total (chunk empty => excl = total)
}

__global__ void scatter_kernel(const int* __restrict__ ei, int* __restrict__ row_fill,
                               int* __restrict__ ssrc) {
    int idx = blockIdx.x * 256 + threadIdx.x;
    if (idx < N_EDGES) {
        int s = ei[idx];
        int d = ei[N_EDGES + idx];
        if (s < 0 || s >= N_NODES || d < 0 || d >= N_NODES) return;  // defensive
        int pos = atomicAdd(&row_fill[d], 1);
        if (pos >= 0 && pos < E_TOT) ssrc[pos] = s;
    } else if (idx < E_TOT) {
        int nd = idx - N_EDGES;
        int pos = atomicAdd(&row_fill[nd], 1);
        if (pos >= 0 && pos < E_TOT) ssrc[pos] = nd;
    }
}

// ---------------------------------------------------------------------------
// SGEMM: C[M,N] = A[M,K] * B[K,N], fp32, 128x128 tile, 8x8 per thread
// ---------------------------------------------------------------------------
__global__ __launch_bounds__(256) void sgemm_kernel(const float* __restrict__ A,
                                                    const float* __restrict__ B,
                                                    float* __restrict__ C,
                                                    int M, int N, int K) {
    __shared__ __align__(16) float As[8][132];
    __shared__ __align__(16) float Bs[8][132];
    const int tid = threadIdx.x;
    const int tileM = blockIdx.x * 128;
    const int tileN = blockIdx.y * 128;
    const int tx = tid & 15, ty = tid >> 4;

    float acc[8][8] = {};

    const int mA = tid >> 1;              // 0..127
    const int kA = (tid & 1) * 4;         // 0 or 4
    const int rowA = tileM + mA;
    const bool rowAok = rowA < M;
    const float* Aptr = A + (size_t)rowA * K + kA;

    const int kB = tid >> 5;              // 0..7
    const int nB = (tid & 31) * 4;        // 0..124
    const float* Bptr = B + (size_t)kB * N + tileN + nB;

    for (int kk = 0; kk < K; kk += 8) {
        float4 av = make_float4(0.f, 0.f, 0.f, 0.f);
        if (rowAok) av = *reinterpret_cast<const float4*>(Aptr + kk);
        float4 bv = *reinterpret_cast<const float4*>(Bptr + (size_t)kk * N);
        __syncthreads();
        As[kA + 0][mA] = av.x;
        As[kA + 1][mA] = av.y;
        As[kA + 2][mA] = av.z;
        As[kA + 3][mA] = av.w;
        *reinterpret_cast<float4*>(&Bs[kB][nB]) = bv;
        __syncthreads();
#pragma unroll
        for (int k = 0; k < 8; ++k) {
            float4 a0 = *reinterpret_cast<const float4*>(&As[k][ty * 8]);
            float4 a1 = *reinterpret_cast<const float4*>(&As[k][ty * 8 + 4]);
            float4 b0 = *reinterpret_cast<const float4*>(&Bs[k][tx * 8]);
            float4 b1 = *reinterpret_cast<const float4*>(&Bs[k][tx * 8 + 4]);
            float a[8] = {a0.x, a0.y, a0.z, a0.w, a1.x, a1.y, a1.z, a1.w};
            float b[8] = {b0.x, b0.y, b0.z, b0.w, b1.x, b1.y, b1.z, b1.w};
#pragma unroll
            for (int i = 0; i < 8; ++i)
#pragma unroll
                for (int j = 0; j < 8; ++j)
                    acc[i][j] += a[i] * b[j];
        }
    }
#pragma unroll
    for (int i = 0; i < 8; ++i) {
        int row = tileM + ty * 8 + i;
        if (row < M) {
            float4 c0 = make_float4(acc[i][0], acc[i][1], acc[i][2], acc[i][3]);
            float4 c1 = make_float4(acc[i][4], acc[i][5], acc[i][6], acc[i][7]);
            float* cp = C + (size_t)row * N + tileN + tx * 8;
            *reinterpret_cast<float4*>(cp) = c0;
            *reinterpret_cast<float4*>(cp + 4) = c1;
        }
    }
}

// ---------------------------------------------------------------------------
// Attention score dots
// ---------------------------------------------------------------------------
__global__ __launch_bounds__(256) void att1_kernel(const float* __restrict__ h1,
                                                   const float* __restrict__ att_src,
                                                   const float* __restrict__ att_dst,
                                                   float* __restrict__ a_src_o,
                                                   float* __restrict__ a_dst_o) {
    int node = blockIdx.x * 4 + (threadIdx.x >> 6);
    int lane = threadIdx.x & 63;
    float4 hv = reinterpret_cast<const float4*>(h1)[(size_t)node * 64 + lane];
    float4 as = reinterpret_cast<const float4*>(att_src)[lane];
    float4 ad = reinterpret_cast<const float4*>(att_dst)[lane];
    float ps = hv.x * as.x + hv.y * as.y + hv.z * as.z + hv.w * as.w;
    float pd = hv.x * ad.x + hv.y * ad.y + hv.z * ad.z + hv.w * ad.w;
#pragma unroll
    for (int off = 1; off < 16; off <<= 1) {
        ps += __shfl_xor(ps, off);
        pd += __shfl_xor(pd, off);
    }
    if ((lane & 15) == 0) {
        int hd = lane >> 4;
        a_src_o[node * 4 + hd] = ps;
        a_dst_o[node * 4 + hd] = pd;
    }
}

__global__ __launch_bounds__(256) void att2_kernel(const float* __restrict__ h2,
                                                   const float* __restrict__ att_src,
                                                   const float* __restrict__ att_dst,
                                                   float* __restrict__ a_src_o,
                                                   float* __restrict__ a_dst_o) {
    int node = blockIdx.x * 4 + (threadIdx.x >> 6);
    int lane = threadIdx.x & 63;
    float2 hv = reinterpret_cast<const float2*>(h2)[(size_t)node * 64 + lane];
    float2 as = reinterpret_cast<const float2*>(att_src)[lane];
    float2 ad = reinterpret_cast<const float2*>(att_dst)[lane];
    float ps = hv.x * as.x + hv.y * as.y;
    float pd = hv.x * ad.x + hv.y * ad.y;
#pragma unroll
    for (int off = 1; off < 64; off <<= 1) {
        ps += __shfl_xor(ps, off);
        pd += __shfl_xor(pd, off);
    }
    if (lane == 0) {
        a_src_o[node] = ps;
        a_dst_o[node] = pd;
    }
}

__device__ __forceinline__ float lrelu(float x) { return x > 0.f ? x : NEG_SLOPE * x; }

// ---------------------------------------------------------------------------
// Edge aggregation, layer 1: one wave per destination node, 4 heads x 64 ch.
// Phase B is 4-way unrolled with independent accumulators so 4 row-gathers
// are in flight per wave (round-3 profile: 1-deep chain -> only 46% HBM peak).
// ---------------------------------------------------------------------------
__global__ __launch_bounds__(256) void edge1_kernel(const int* __restrict__ row_ptr,
                                                    const int* __restrict__ ssrc,
                                                    const float* __restrict__ h1,
                                                    const float* __restrict__ a_src,
                                                    const float* __restrict__ a_dst,
                                                    const float* __restrict__ bias,
                                                    float* __restrict__ out) {
    int node = blockIdx.x * 4 + (threadIdx.x >> 6);
    int lane = threadIdx.x & 63;
    int start = row_ptr[node], end = row_ptr[node + 1];
    float ad0 = a_dst[node * 4 + 0];
    float ad1 = a_dst[node * 4 + 1];
    float ad2 = a_dst[node * 4 + 2];
    float ad3 = a_dst[node * 4 + 3];

    // Phase A: softmax denominator per head (max-shift skipped: alphas are O(1))
    float s0 = 0.f, s1 = 0.f, s2 = 0.f, s3 = 0.f;
    for (int e = start + lane; e < end; e += 64) {
        int si = ssrc[e];
        float4 av = reinterpret_cast<const float4*>(a_src)[si];
        s0 += __expf(lrelu(av.x + ad0));
        s1 += __expf(lrelu(av.y + ad1));
        s2 += __expf(lrelu(av.z + ad2));
        s3 += __expf(lrelu(av.w + ad3));
    }
#pragma unroll
    for (int off = 1; off < 64; off <<= 1) {
        s0 += __shfl_xor(s0, off);
        s1 += __shfl_xor(s1, off);
        s2 += __shfl_xor(s2, off);
        s3 += __shfl_xor(s3, off);
    }
    int hd = lane >> 4;
    float Ssel = hd == 0 ? s0 : hd == 1 ? s1 : hd == 2 ? s2 : s3;
    float adh  = hd == 0 ? ad0 : hd == 1 ? ad1 : hd == 2 ? ad2 : ad3;
    float inv = 1.0f / (Ssel + EPS_F);

    // Phase B: weighted gather-accumulate; lane holds flat channels lane*4..+3
    const float4* h1v = reinterpret_cast<const float4*>(h1);
    float4 acc0 = make_float4(0.f, 0.f, 0.f, 0.f);
    float4 acc1 = make_float4(0.f, 0.f, 0.f, 0.f);
    float4 acc2 = make_float4(0.f, 0.f, 0.f, 0.f);
    float4 acc3 = make_float4(0.f, 0.f, 0.f, 0.f);
    int e = start;
    for (; e + 4 <= end; e += 4) {
        int si0 = ssrc[e + 0];
        int si1 = ssrc[e + 1];
        int si2 = ssrc[e + 2];
        int si3 = ssrc[e + 3];
        float r0 = a_src[si0 * 4 + hd];
        float r1 = a_src[si1 * 4 + hd];
        float r2 = a_src[si2 * 4 + hd];
        float r3 = a_src[si3 * 4 + hd];
        float4 v0 = h1v[(size_t)si0 * 64 + lane];
        float4 v1 = h1v[(size_t)si1 * 64 + lane];
        float4 v2 = h1v[(size_t)si2 * 64 + lane];
        float4 v3 = h1v[(size_t)si3 * 64 + lane];
        float w0 = __expf(lrelu(r0 + adh)) * inv;
        float w1 = __expf(lrelu(r1 + adh)) * inv;
        float w2 = __expf(lrelu(r2 + adh)) * inv;
        float w3 = __expf(lrelu(r3 + adh)) * inv;
        acc0.x += w0 * v0.x; acc0.y += w0 * v0.y; acc0.z += w0 * v0.z; acc0.w += w0 * v0.w;
        acc1.x += w1 * v1.x; acc1.y += w1 * v1.y; acc1.z += w1 * v1.z; acc1.w += w1 * v1.w;
        acc2.x += w2 * v2.x; acc2.y += w2 * v2.y; acc2.z += w2 * v2.z; acc2.w += w2 * v2.w;
        acc3.x += w3 * v3.x; acc3.y += w3 * v3.y; acc3.z += w3 * v3.z; acc3.w += w3 * v3.w;
    }
    for (; e < end; ++e) {
        int si = ssrc[e];
        float w = __expf(lrelu(a_src[si * 4 + hd] + adh)) * inv;
        float4 hv = h1v[(size_t)si * 64 + lane];
        acc0.x += w * hv.x; acc0.y += w * hv.y; acc0.z += w * hv.z; acc0.w += w * hv.w;
    }
    float4 acc;
    acc.x = (acc0.x + acc1.x) + (acc2.x + acc3.x);
    acc.y = (acc0.y + acc1.y) + (acc2.y + acc3.y);
    acc.z = (acc0.z + acc1.z) + (acc2.z + acc3.z);
    acc.w = (acc0.w + acc1.w) + (acc2.w + acc3.w);
    float4 bv = reinterpret_cast<const float4*>(bias)[lane];
    acc.x = fmaxf(acc.x + bv.x, 0.f);
    acc.y = fmaxf(acc.y + bv.y, 0.f);
    acc.z = fmaxf(acc.z + bv.z, 0.f);
    acc.w = fmaxf(acc.w + bv.w, 0.f);
    reinterpret_cast<float4*>(out)[(size_t)node * 64 + lane] = acc;
}

// ---------------------------------------------------------------------------
// Edge aggregation, layer 2: one wave per destination node, 1 head x 128 ch
// ---------------------------------------------------------------------------
__global__ __launch_bounds__(256) void edge2_kernel(const int* __restrict__ row_ptr,
                                                    const int* __restrict__ ssrc,
                                                    const float* __restrict__ h2,
                                                    const float* __restrict__ a_src,
                                                    const float* __restrict__ a_dst,
                                                    const float* __restrict__ bias,
                                                    float* __restrict__ out) {
    int node = blockIdx.x * 4 + (threadIdx.x >> 6);
    int lane = threadIdx.x & 63;
    int start = row_ptr[node], end = row_ptr[node + 1];
    float ad = a_dst[node];

    float s = 0.f;
    for (int e = start + lane; e < end; e += 64) {
        int si = ssrc[e];
        s += __expf(lrelu(a_src[si] + ad));
    }
#pragma unroll
    for (int off = 1; off < 64; off <<= 1) s += __shfl_xor(s, off);
    float inv = 1.0f / (s + EPS_F);

    const float2* h2v = reinterpret_cast<const float2*>(h2);
    float2 acc0 = make_float2(0.f, 0.f);
    float2 acc1 = make_float2(0.f, 0.f);
    float2 acc2 = make_float2(0.f, 0.f);
    float2 acc3 = make_float2(0.f, 0.f);
    int e = start;
    for (; e + 4 <= end; e += 4) {
        int si0 = ssrc[e + 0];
        int si1 = ssrc[e + 1];
        int si2 = ssrc[e + 2];
        int si3 = ssrc[e + 3];
        float r0 = a_src[si0];
        float r1 = a_src[si1];
        float r2 = a_src[si2];
        float r3 = a_src[si3];
        float2 v0 = h2v[(size_t)si0 * 64 + lane];
        float2 v1 = h2v[(size_t)si1 * 64 + lane];
        float2 v2 = h2v[(size_t)si2 * 64 + lane];
        float2 v3 = h2v[(size_t)si3 * 64 + lane];
        float w0 = __expf(lrelu(r0 + ad)) * inv;
        float w1 = __expf(lrelu(r1 + ad)) * inv;
        float w2 = __expf(lrelu(r2 + ad)) * inv;
        float w3 = __expf(lrelu(r3 + ad)) * inv;
        acc0.x += w0 * v0.x; acc0.y += w0 * v0.y;
        acc1.x += w1 * v1.x; acc1.y += w1 * v1.y;
        acc2.x += w2 * v2.x; acc2.y += w2 * v2.y;
        acc3.x += w3 * v3.x; acc3.y += w3 * v3.y;
    }
    for (; e < end; ++e) {
        int si = ssrc[e];
        float w = __expf(lrelu(a_src[si] + ad)) * inv;
        float2 hv = h2v[(size_t)si * 64 + lane];
        acc0.x += w * hv.x; acc0.y += w * hv.y;
    }
    float2 acc;
    acc.x = (acc0.x + acc1.x) + (acc2.x + acc3.x);
    acc.y = (acc0.y + acc1.y) + (acc2.y + acc3.y);
    float2 bv = reinterpret_cast<const float2*>(bias)[lane];
    acc.x = fmaxf(acc.x + bv.x, 0.f);
    acc.y = fmaxf(acc.y + bv.y, 0.f);
    reinterpret_cast<float2*>(out)[(size_t)node * 64 + lane] = acc;
}

// ---------------------------------------------------------------------------
// Pooling: batch is sorted -> per-block running accumulator, flush on change
// ---------------------------------------------------------------------------
__global__ __launch_bounds__(128) void pool_kernel(const float* __restrict__ out2,
                                                   const int* __restrict__ batch,
                                                   float* __restrict__ d_out) {
    int c = threadIdx.x;                 // channel 0..127
    int node0 = blockIdx.x * 128;
    int nodeEnd = node0 + 128; if (nodeEnd > N_NODES) nodeEnd = N_NODES;
    if (node0 >= N_NODES) return;
    int gprev = batch[node0];
    float acc = 0.f;
    for (int node = node0; node < nodeEnd; ++node) {
        int g = batch[node];
        if (g != gprev) {
            if (gprev >= 0 && gprev < N_GRAPHS) atomicAdd(&d_out[gprev * 128 + c], acc);
            acc = 0.f;
            gprev = g;
        }
        acc += out2[(size_t)node * 128 + c];
    }
    if (gprev >= 0 && gprev < N_GRAPHS) atomicAdd(&d_out[gprev * 128 + c], acc);
}

// Graph boundary detection: batch is sorted, so each graph's start index is
// written exactly once (no contended atomics).
__global__ void bounds_kernel(const int* __restrict__ batch, int* __restrict__ gstart) {
    int idx = blockIdx.x * 256 + threadIdx.x;
    if (idx >= N_NODES) return;
    int g = batch[idx];
    if (g < 0) g = 0; if (g >= N_GRAPHS) g = N_GRAPHS - 1;
    if (idx == 0) {
        for (int j = 0; j <= g; ++j) gstart[j] = 0;
    } else {
        int gp = batch[idx - 1];
        if (gp < 0) gp = 0; if (gp >= N_GRAPHS) gp = N_GRAPHS - 1;
        for (int j = gp + 1; j <= g; ++j) gstart[j] = idx;
    }
    if (idx == N_NODES - 1) {
        for (int j = g + 1; j <= N_GRAPHS; ++j) gstart[j] = N_NODES;
    }
}

__global__ void final_kernel(float* __restrict__ d_out, const int* __restrict__ gstart) {
    int idx = blockIdx.x * 256 + threadIdx.x;
    if (idx < N_GRAPHS * 128) {
        int g = idx >> 7;
        float c = (float)(gstart[g + 1] - gstart[g]);
        if (c < 1.f) c = 1.f;
        d_out[idx] = d_out[idx] / c;
    }
}

// ---------------------------------------------------------------------------
extern "C" void kernel_launch(void* const* d_in, const int* in_sizes, int n_in,
                              void* d_out_v, int out_size, void* d_ws, size_t ws_size,
                              hipStream_t stream) {
    const float* x      = (const float*)d_in[0];
    const float* W1     = (const float*)d_in[1];
    const float* att_s1 = (const float*)d_in[2];
    const float* att_d1 = (const float*)d_in[3];
    const float* bias1  = (const float*)d_in[4];
    const float* W2     = (const float*)d_in[5];
    const float* att_s2 = (const float*)d_in[6];
    const float* att_d2 = (const float*)d_in[7];
    const float* bias2  = (const float*)d_in[8];
    const int*   ei     = (const int*)d_in[9];
    const int*   batch  = (const int*)d_in[10];
    float* d_out = (float*)d_out_v;

    // Workspace layout (floats)
    float* ws = (float*)d_ws;
    float* h1     = ws;                        // 12,800,000 (N*256)  [reused: h2 + out2]
    float* out1   = h1 + 12800000;             // 12,800,000
    float* h2     = h1;                        // N*128 = 6,400,000 (h1 dead by then)
    float* out2   = h1 + 6400000;              // N*128 = 6,400,000
    float* a_src1 = out1 + 12800000;           // N*4
    float* a_dst1 = a_src1 + 200000;           // N*4
    float* a_src2 = a_dst1 + 200000;           // N
    float* a_dst2 = a_src2 + 50000;            // N
    int* hist     = (int*)(a_dst2 + 50000);    // N
    int* row_ptr  = hist + 50000;              // N+1 (padded to 50016)
    int* row_fill = row_ptr + 50016;           // N (padded to 50016)
    int* ssrc     = row_fill + 50016;          // E_TOT
    int* gstart   = ssrc + E_TOT;              // N_GRAPHS+1

    // Zero what must be zero
    hipMemsetAsync(hist, 0, N_NODES * sizeof(int), stream);
    hipMemsetAsync(d_out, 0, N_GRAPHS * 128 * sizeof(float), stream);

    // CSR build
    hist_kernel<<<(E_TOT + 255) / 256, 256, 0, stream>>>(ei, hist);
    scan_kernel<<<1, 1024, 0, stream>>>(hist, row_ptr, row_fill);
    scatter_kernel<<<(E_TOT + 255) / 256, 256, 0, stream>>>(ei, row_fill, ssrc);
    bounds_kernel<<<(N_NODES + 255) / 256, 256, 0, stream>>>(batch, gstart);

    // Layer 1
    {
        dim3 g((N_NODES + 127) / 128, H1C / 128);
        sgemm_kernel<<<g, 256, 0, stream>>>(x, W1, h1, N_NODES, H1C, IN_C);
    }
    att1_kernel<<<N_NODES / 4, 256, 0, stream>>>(h1, att_s1, att_d1, a_src1, a_dst1);
    edge1_kernel<<<N_NODES / 4, 256, 0, stream>>>(row_ptr, ssrc, h1, a_src1, a_dst1, bias1, out1);

    // Layer 2
    {
        dim3 g((N_NODES + 127) / 128, OUT_C / 128);
        sgemm_kernel<<<g, 256, 0, stream>>>(out1, W2, h2, N_NODES, OUT_C, H1C);
    }
    att2_kernel<<<N_NODES / 4, 256, 0, stream>>>(h2, att_s2, att_d2, a_src2, a_dst2);
    edge2_kernel<<<N_NODES / 4, 256, 0, stream>>>(row_ptr, ssrc, h2, a_src2, a_dst2, bias2, out2);

    // Pooling
    pool_kernel<<<(N_NODES + 127) / 128, 128, 0, stream>>>(out2, batch, d_out);
    final_kernel<<<(N_GRAPHS * 128 + 255) / 256, 256, 0, stream>>>(d_out, gstart);
}

// Round 6
// 609.648 us; speedup vs baseline: 1.4693x; 1.1496x over previous
//
#include <hip/hip_runtime.h>
#include <hip/hip_bf16.h>
#include <hip/hip_fp16.h>

// Problem constants (fixed by the reference setup)
#define N_NODES 50000
#define N_EDGES 800000
#define E_TOT   (N_EDGES + N_NODES)   // 850000 (self-loops appended)
#define IN_C    256
#define H1C     256                    // HEADS * HID_C = 4*64
#define HEADS   4
#define HID_C   64
#define OUT_C   128
#define N_GRAPHS 100
#define NEG_SLOPE 0.2f
#define EPS_F 1e-16f

// ---------------------------------------------------------------------------
// CSR build: histogram -> scan -> scatter
// ---------------------------------------------------------------------------
__global__ void hist_kernel(const int* __restrict__ ei, int* __restrict__ hist) {
    int idx = blockIdx.x * 256 + threadIdx.x;
    if (idx < N_EDGES) {
        int d = ei[N_EDGES + idx];                // dst row
        if (d >= 0 && d < N_NODES) atomicAdd(&hist[d], 1);
    } else if (idx < E_TOT) {
        atomicAdd(&hist[idx - N_EDGES], 1);       // self loop
    }
}

__global__ __launch_bounds__(1024) void scan_kernel(const int* __restrict__ hist,
                                                    int* __restrict__ row_ptr,
                                                    int* __restrict__ row_fill) {
    __shared__ int sums[1024];
    const int CH = (N_NODES + 1023) / 1024;       // 49
    int t = threadIdx.x;
    int begin = t * CH;
    int end = begin + CH; if (end > N_NODES) end = N_NODES;
    if (begin > N_NODES) begin = N_NODES;
    int s = 0;
    for (int i = begin; i < end; ++i) s += hist[i];
    sums[t] = s;
    __syncthreads();
    for (int off = 1; off < 1024; off <<= 1) {
        int v = 0;
        if (t >= off) v = sums[t - off];
        __syncthreads();
        sums[t] += v;
        __syncthreads();
    }
    int excl = sums[t] - s;       // exclusive prefix of this chunk
    int run = excl;
    for (int i = begin; i < end; ++i) {
        row_ptr[i] = run;
        row_fill[i] = run;
        run += hist[i];
    }
    if (t == 1023) row_ptr[N_NODES] = run;   // grand total (chunk empty => excl = total)
}

__global__ void scatter_kernel(const int* __restrict__ ei, int* __restrict__ row_fill,
                               int* __restrict__ ssrc) {
    int idx = blockIdx.x * 256 + threadIdx.x;
    if (idx < N_EDGES) {
        int s = ei[idx];
        int d = ei[N_EDGES + idx];
        if (s < 0 || s >= N_NODES || d < 0 || d >= N_NODES) return;  // defensive
        int pos = atomicAdd(&row_fill[d], 1);
        if (pos >= 0 && pos < E_TOT) ssrc[pos] = s;
    } else if (idx < E_TOT) {
        int nd = idx - N_EDGES;
        int pos = atomicAdd(&row_fill[nd], 1);
        if (pos >= 0 && pos < E_TOT) ssrc[pos] = nd;
    }
}

// ---------------------------------------------------------------------------
// SGEMM with fp16 output: C[M,N] = fp16(A[M,K] * B[K,N])
// fp32 accumulate, 128x128 tile, 8x8 per thread. fp16 h halves the edge-gather
// bytes (round-4 profile: edge kernels throughput-bound on L2-miss traffic).
// NOTE round-5 bug: C-store address must include tileN (layer 1 has 2 N-tiles).
// ---------------------------------------------------------------------------
__global__ __launch_bounds__(256) void sgemm_h_kernel(const float* __restrict__ A,
                                                      const float* __restrict__ B,
                                                      __half* __restrict__ C,
                                                      int M, int N, int K) {
    __shared__ __align__(16) float As[8][132];
    __shared__ __align__(16) float Bs[8][132];
    const int tid = threadIdx.x;
    const int tileM = blockIdx.x * 128;
    const int tileN = blockIdx.y * 128;
    const int tx = tid & 15, ty = tid >> 4;

    float acc[8][8] = {};

    const int mA = tid >> 1;              // 0..127
    const int kA = (tid & 1) * 4;         // 0 or 4
    const int rowA = tileM + mA;
    const bool rowAok = rowA < M;
    const float* Aptr = A + (size_t)rowA * K + kA;

    const int kB = tid >> 5;              // 0..7
    const int nB = (tid & 31) * 4;        // 0..124
    const float* Bptr = B + (size_t)kB * N + tileN + nB;

    for (int kk = 0; kk < K; kk += 8) {
        float4 av = make_float4(0.f, 0.f, 0.f, 0.f);
        if (rowAok) av = *reinterpret_cast<const float4*>(Aptr + kk);
        float4 bv = *reinterpret_cast<const float4*>(Bptr + (size_t)kk * N);
        __syncthreads();
        As[kA + 0][mA] = av.x;
        As[kA + 1][mA] = av.y;
        As[kA + 2][mA] = av.z;
        As[kA + 3][mA] = av.w;
        *reinterpret_cast<float4*>(&Bs[kB][nB]) = bv;
        __syncthreads();
#pragma unroll
        for (int k = 0; k < 8; ++k) {
            float4 a0 = *reinterpret_cast<const float4*>(&As[k][ty * 8]);
            float4 a1 = *reinterpret_cast<const float4*>(&As[k][ty * 8 + 4]);
            float4 b0 = *reinterpret_cast<const float4*>(&Bs[k][tx * 8]);
            float4 b1 = *reinterpret_cast<const float4*>(&Bs[k][tx * 8 + 4]);
            float a[8] = {a0.x, a0.y, a0.z, a0.w, a1.x, a1.y, a1.z, a1.w};
            float b[8] = {b0.x, b0.y, b0.z, b0.w, b1.x, b1.y, b1.z, b1.w};
#pragma unroll
            for (int i = 0; i < 8; ++i)
#pragma unroll
                for (int j = 0; j < 8; ++j)
                    acc[i][j] += a[i] * b[j];
        }
    }
#pragma unroll
    for (int i = 0; i < 8; ++i) {
        int row = tileM + ty * 8 + i;
        if (row < M) {
            union { __half h[8]; uint4 u; } cv;
#pragma unroll
            for (int j = 0; j < 8; ++j) cv.h[j] = __float2half(acc[i][j]);
            *reinterpret_cast<uint4*>(C + (size_t)row * N + tileN + tx * 8) = cv.u;
        }
    }
}

// ---------------------------------------------------------------------------
// Attention score dots (fp16 h, fp32 math)
// ---------------------------------------------------------------------------
__global__ __launch_bounds__(256) void att1_kernel(const __half* __restrict__ h1h,
                                                   const float* __restrict__ att_src,
                                                   const float* __restrict__ att_dst,
                                                   float* __restrict__ a_src_o,
                                                   float* __restrict__ a_dst_o) {
    int node = blockIdx.x * 4 + (threadIdx.x >> 6);
    int lane = threadIdx.x & 63;
    uint2 raw = reinterpret_cast<const uint2*>(h1h)[(size_t)node * 64 + lane];
    float2 f01 = __half22float2(*reinterpret_cast<const __half2*>(&raw.x));
    float2 f23 = __half22float2(*reinterpret_cast<const __half2*>(&raw.y));
    float4 as = reinterpret_cast<const float4*>(att_src)[lane];
    float4 ad = reinterpret_cast<const float4*>(att_dst)[lane];
    float ps = f01.x * as.x + f01.y * as.y + f23.x * as.z + f23.y * as.w;
    float pd = f01.x * ad.x + f01.y * ad.y + f23.x * ad.z + f23.y * ad.w;
#pragma unroll
    for (int off = 1; off < 16; off <<= 1) {
        ps += __shfl_xor(ps, off);
        pd += __shfl_xor(pd, off);
    }
    if ((lane & 15) == 0) {
        int hd = lane >> 4;
        a_src_o[node * 4 + hd] = ps;
        a_dst_o[node * 4 + hd] = pd;
    }
}

__global__ __launch_bounds__(256) void att2_kernel(const __half* __restrict__ h2h,
                                                   const float* __restrict__ att_src,
                                                   const float* __restrict__ att_dst,
                                                   float* __restrict__ a_src_o,
                                                   float* __restrict__ a_dst_o) {
    int node = blockIdx.x * 4 + (threadIdx.x >> 6);
    int lane = threadIdx.x & 63;
    __half2 raw = reinterpret_cast<const __half2*>(h2h)[(size_t)node * 64 + lane];
    float2 hv = __half22float2(raw);
    float2 as = reinterpret_cast<const float2*>(att_src)[lane];
    float2 ad = reinterpret_cast<const float2*>(att_dst)[lane];
    float ps = hv.x * as.x + hv.y * as.y;
    float pd = hv.x * ad.x + hv.y * ad.y;
#pragma unroll
    for (int off = 1; off < 64; off <<= 1) {
        ps += __shfl_xor(ps, off);
        pd += __shfl_xor(pd, off);
    }
    if (lane == 0) {
        a_src_o[node] = ps;
        a_dst_o[node] = pd;
    }
}

__device__ __forceinline__ float lrelu(float x) { return x > 0.f ? x : NEG_SLOPE * x; }

// ---------------------------------------------------------------------------
// Edge aggregation, layer 1: one wave per destination node, 4 heads x 64 ch.
// fp16 gather payload (8 B/lane), fp32 accumulate, 4-way unrolled.
// ---------------------------------------------------------------------------
__global__ __launch_bounds__(256) void edge1_kernel(const int* __restrict__ row_ptr,
                                                    const int* __restrict__ ssrc,
                                                    const __half* __restrict__ h1h,
                                                    const float* __restrict__ a_src,
                                                    const float* __restrict__ a_dst,
                                                    const float* __restrict__ bias,
                                                    float* __restrict__ out) {
    int node = blockIdx.x * 4 + (threadIdx.x >> 6);
    int lane = threadIdx.x & 63;
    int start = row_ptr[node], end = row_ptr[node + 1];
    float ad0 = a_dst[node * 4 + 0];
    float ad1 = a_dst[node * 4 + 1];
    float ad2 = a_dst[node * 4 + 2];
    float ad3 = a_dst[node * 4 + 3];

    // Phase A: softmax denominator per head (max-shift skipped: alphas are O(1))
    float s0 = 0.f, s1 = 0.f, s2 = 0.f, s3 = 0.f;
    for (int e = start + lane; e < end; e += 64) {
        int si = ssrc[e];
        float4 av = reinterpret_cast<const float4*>(a_src)[si];
        s0 += __expf(lrelu(av.x + ad0));
        s1 += __expf(lrelu(av.y + ad1));
        s2 += __expf(lrelu(av.z + ad2));
        s3 += __expf(lrelu(av.w + ad3));
    }
#pragma unroll
    for (int off = 1; off < 64; off <<= 1) {
        s0 += __shfl_xor(s0, off);
        s1 += __shfl_xor(s1, off);
        s2 += __shfl_xor(s2, off);
        s3 += __shfl_xor(s3, off);
    }
    int hd = lane >> 4;
    float Ssel = hd == 0 ? s0 : hd == 1 ? s1 : hd == 2 ? s2 : s3;
    float adh  = hd == 0 ? ad0 : hd == 1 ? ad1 : hd == 2 ? ad2 : ad3;
    float inv = 1.0f / (Ssel + EPS_F);

    // Phase B: weighted gather-accumulate; lane holds flat channels lane*4..+3
    const uint2* h1v = reinterpret_cast<const uint2*>(h1h);
    float4 acc0 = make_float4(0.f, 0.f, 0.f, 0.f);
    float4 acc1 = make_float4(0.f, 0.f, 0.f, 0.f);
    float4 acc2 = make_float4(0.f, 0.f, 0.f, 0.f);
    float4 acc3 = make_float4(0.f, 0.f, 0.f, 0.f);
    int e = start;
    for (; e + 4 <= end; e += 4) {
        int si0 = ssrc[e + 0];
        int si1 = ssrc[e + 1];
        int si2 = ssrc[e + 2];
        int si3 = ssrc[e + 3];
        float r0 = a_src[si0 * 4 + hd];
        float r1 = a_src[si1 * 4 + hd];
        float r2 = a_src[si2 * 4 + hd];
        float r3 = a_src[si3 * 4 + hd];
        uint2 q0 = h1v[(size_t)si0 * 64 + lane];
        uint2 q1 = h1v[(size_t)si1 * 64 + lane];
        uint2 q2 = h1v[(size_t)si2 * 64 + lane];
        uint2 q3 = h1v[(size_t)si3 * 64 + lane];
        float w0 = __expf(lrelu(r0 + adh)) * inv;
        float w1 = __expf(lrelu(r1 + adh)) * inv;
        float w2 = __expf(lrelu(r2 + adh)) * inv;
        float w3 = __expf(lrelu(r3 + adh)) * inv;
        float2 f0a = __half22float2(*reinterpret_cast<const __half2*>(&q0.x));
        float2 f0b = __half22float2(*reinterpret_cast<const __half2*>(&q0.y));
        float2 f1a = __half22float2(*reinterpret_cast<const __half2*>(&q1.x));
        float2 f1b = __half22float2(*reinterpret_cast<const __half2*>(&q1.y));
        float2 f2a = __half22float2(*reinterpret_cast<const __half2*>(&q2.x));
        float2 f2b = __half22float2(*reinterpret_cast<const __half2*>(&q2.y));
        float2 f3a = __half22float2(*reinterpret_cast<const __half2*>(&q3.x));
        float2 f3b = __half22float2(*reinterpret_cast<const __half2*>(&q3.y));
        acc0.x += w0 * f0a.x; acc0.y += w0 * f0a.y; acc0.z += w0 * f0b.x; acc0.w += w0 * f0b.y;
        acc1.x += w1 * f1a.x; acc1.y += w1 * f1a.y; acc1.z += w1 * f1b.x; acc1.w += w1 * f1b.y;
        acc2.x += w2 * f2a.x; acc2.y += w2 * f2a.y; acc2.z += w2 * f2b.x; acc2.w += w2 * f2b.y;
        acc3.x += w3 * f3a.x; acc3.y += w3 * f3a.y; acc3.z += w3 * f3b.x; acc3.w += w3 * f3b.y;
    }
    for (; e < end; ++e) {
        int si = ssrc[e];
        float w = __expf(lrelu(a_src[si * 4 + hd] + adh)) * inv;
        uint2 q = h1v[(size_t)si * 64 + lane];
        float2 fa = __half22float2(*reinterpret_cast<const __half2*>(&q.x));
        float2 fb = __half22float2(*reinterpret_cast<const __half2*>(&q.y));
        acc0.x += w * fa.x; acc0.y += w * fa.y; acc0.z += w * fb.x; acc0.w += w * fb.y;
    }
    float4 acc;
    acc.x = (acc0.x + acc1.x) + (acc2.x + acc3.x);
    acc.y = (acc0.y + acc1.y) + (acc2.y + acc3.y);
    acc.z = (acc0.z + acc1.z) + (acc2.z + acc3.z);
    acc.w = (acc0.w + acc1.w) + (acc2.w + acc3.w);
    float4 bv = reinterpret_cast<const float4*>(bias)[lane];
    acc.x = fmaxf(acc.x + bv.x, 0.f);
    acc.y = fmaxf(acc.y + bv.y, 0.f);
    acc.z = fmaxf(acc.z + bv.z, 0.f);
    acc.w = fmaxf(acc.w + bv.w, 0.f);
    reinterpret_cast<float4*>(out)[(size_t)node * 64 + lane] = acc;
}

// ---------------------------------------------------------------------------
// Edge aggregation, layer 2: one wave per destination node, 1 head x 128 ch.
// fp16 gather payload (4 B/lane), fp32 accumulate, 4-way unrolled.
// ---------------------------------------------------------------------------
__global__ __launch_bounds__(256) void edge2_kernel(const int* __restrict__ row_ptr,
                                                    const int* __restrict__ ssrc,
                                                    const __half* __restrict__ h2h,
                                                    const float* __restrict__ a_src,
                                                    const float* __restrict__ a_dst,
                                                    const float* __restrict__ bias,
                                                    float* __restrict__ out) {
    int node = blockIdx.x * 4 + (threadIdx.x >> 6);
    int lane = threadIdx.x & 63;
    int start = row_ptr[node], end = row_ptr[node + 1];
    float ad = a_dst[node];

    float s = 0.f;
    for (int e = start + lane; e < end; e += 64) {
        int si = ssrc[e];
        s += __expf(lrelu(a_src[si] + ad));
    }
#pragma unroll
    for (int off = 1; off < 64; off <<= 1) s += __shfl_xor(s, off);
    float inv = 1.0f / (s + EPS_F);

    const __half2* h2v = reinterpret_cast<const __half2*>(h2h);
    float2 acc0 = make_float2(0.f, 0.f);
    float2 acc1 = make_float2(0.f, 0.f);
    float2 acc2 = make_float2(0.f, 0.f);
    float2 acc3 = make_float2(0.f, 0.f);
    int e = start;
    for (; e + 4 <= end; e += 4) {
        int si0 = ssrc[e + 0];
        int si1 = ssrc[e + 1];
        int si2 = ssrc[e + 2];
        int si3 = ssrc[e + 3];
        float r0 = a_src[si0];
        float r1 = a_src[si1];
        float r2 = a_src[si2];
        float r3 = a_src[si3];
        __half2 q0 = h2v[(size_t)si0 * 64 + lane];
        __half2 q1 = h2v[(size_t)si1 * 64 + lane];
        __half2 q2 = h2v[(size_t)si2 * 64 + lane];
        __half2 q3 = h2v[(size_t)si3 * 64 + lane];
        float w0 = __expf(lrelu(r0 + ad)) * inv;
        float w1 = __expf(lrelu(r1 + ad)) * inv;
        float w2 = __expf(lrelu(r2 + ad)) * inv;
        float w3 = __expf(lrelu(r3 + ad)) * inv;
        float2 v0 = __half22float2(q0);
        float2 v1 = __half22float2(q1);
        float2 v2 = __half22float2(q2);
        float2 v3 = __half22float2(q3);
        acc0.x += w0 * v0.x; acc0.y += w0 * v0.y;
        acc1.x += w1 * v1.x; acc1.y += w1 * v1.y;
        acc2.x += w2 * v2.x; acc2.y += w2 * v2.y;
        acc3.x += w3 * v3.x; acc3.y += w3 * v3.y;
    }
    for (; e < end; ++e) {
        int si = ssrc[e];
        float w = __expf(lrelu(a_src[si] + ad)) * inv;
        float2 hv = __half22float2(h2v[(size_t)si * 64 + lane]);
        acc0.x += w * hv.x; acc0.y += w * hv.y;
    }
    float2 acc;
    acc.x = (acc0.x + acc1.x) + (acc2.x + acc3.x);
    acc.y = (acc0.y + acc1.y) + (acc2.y + acc3.y);
    float2 bv = reinterpret_cast<const float2*>(bias)[lane];
    acc.x = fmaxf(acc.x + bv.x, 0.f);
    acc.y = fmaxf(acc.y + bv.y, 0.f);
    reinterpret_cast<float2*>(out)[(size_t)node * 64 + lane] = acc;
}

// ---------------------------------------------------------------------------
// Pooling: batch is sorted -> per-block running accumulator, flush on change
// ---------------------------------------------------------------------------
__global__ __launch_bounds__(128) void pool_kernel(const float* __restrict__ out2,
                                                   const int* __restrict__ batch,
                                                   float* __restrict__ d_out) {
    int c = threadIdx.x;                 // channel 0..127
    int node0 = blockIdx.x * 128;
    int nodeEnd = node0 + 128; if (nodeEnd > N_NODES) nodeEnd = N_NODES;
    if (node0 >= N_NODES) return;
    int gprev = batch[node0];
    float acc = 0.f;
    for (int node = node0; node < nodeEnd; ++node) {
        int g = batch[node];
        if (g != gprev) {
            if (gprev >= 0 && gprev < N_GRAPHS) atomicAdd(&d_out[gprev * 128 + c], acc);
            acc = 0.f;
            gprev = g;
        }
        acc += out2[(size_t)node * 128 + c];
    }
    if (gprev >= 0 && gprev < N_GRAPHS) atomicAdd(&d_out[gprev * 128 + c], acc);
}

// Graph boundary detection: batch is sorted, so each graph's start index is
// written exactly once (no contended atomics).
__global__ void bounds_kernel(const int* __restrict__ batch, int* __restrict__ gstart) {
    int idx = blockIdx.x * 256 + threadIdx.x;
    if (idx >= N_NODES) return;
    int g = batch[idx];
    if (g < 0) g = 0; if (g >= N_GRAPHS) g = N_GRAPHS - 1;
    if (idx == 0) {
        for (int j = 0; j <= g; ++j) gstart[j] = 0;
    } else {
        int gp = batch[idx - 1];
        if (gp < 0) gp = 0; if (gp >= N_GRAPHS) gp = N_GRAPHS - 1;
        for (int j = gp + 1; j <= g; ++j) gstart[j] = idx;
    }
    if (idx == N_NODES - 1) {
        for (int j = g + 1; j <= N_GRAPHS; ++j) gstart[j] = N_NODES;
    }
}

__global__ void final_kernel(float* __restrict__ d_out, const int* __restrict__ gstart) {
    int idx = blockIdx.x * 256 + threadIdx.x;
    if (idx < N_GRAPHS * 128) {
        int g = idx >> 7;
        float c = (float)(gstart[g + 1] - gstart[g]);
        if (c < 1.f) c = 1.f;
        d_out[idx] = d_out[idx] / c;
    }
}

// ---------------------------------------------------------------------------
extern "C" void kernel_launch(void* const* d_in, const int* in_sizes, int n_in,
                              void* d_out_v, int out_size, void* d_ws, size_t ws_size,
                              hipStream_t stream) {
    const float* x      = (const float*)d_in[0];
    const float* W1     = (const float*)d_in[1];
    const float* att_s1 = (const float*)d_in[2];
    const float* att_d1 = (const float*)d_in[3];
    const float* bias1  = (const float*)d_in[4];
    const float* W2     = (const float*)d_in[5];
    const float* att_s2 = (const float*)d_in[6];
    const float* att_d2 = (const float*)d_in[7];
    const float* bias2  = (const float*)d_in[8];
    const int*   ei     = (const int*)d_in[9];
    const int*   batch  = (const int*)d_in[10];
    float* d_out = (float*)d_out_v;

    // Workspace layout (float units):
    //  [0, 12.8M)        out1 fp32 (layer-1 output)  ... later reused as out2
    //  [12.8M, 19.2M)    h1h fp16 (12.8M halfs)      ... later reused as h2h
    //  [19.2M, ...)      attention scalars + CSR ints
    float* ws = (float*)d_ws;
    float*  out1   = ws;                                 // 12.8M floats
    __half* h1h    = (__half*)(ws + 12800000);           // 12.8M halfs = 6.4M floats
    __half* h2h    = h1h;                                // 6.4M halfs (h1h dead by then)
    float*  out2   = ws;                                 // 6.4M floats (out1 dead by then)
    float* a_src1 = ws + 19200000;             // N*4
    float* a_dst1 = a_src1 + 200000;           // N*4
    float* a_src2 = a_dst1 + 200000;           // N
    float* a_dst2 = a_src2 + 50000;            // N
    int* hist     = (int*)(a_dst2 + 50000);    // N
    int* row_ptr  = hist + 50000;              // N+1 (padded to 50016)
    int* row_fill = row_ptr + 50016;           // N (padded to 50016)
    int* ssrc     = row_fill + 50016;          // E_TOT
    int* gstart   = ssrc + E_TOT;              // N_GRAPHS+1

    // Zero what must be zero
    hipMemsetAsync(hist, 0, N_NODES * sizeof(int), stream);
    hipMemsetAsync(d_out, 0, N_GRAPHS * 128 * sizeof(float), stream);

    // CSR build
    hist_kernel<<<(E_TOT + 255) / 256, 256, 0, stream>>>(ei, hist);
    scan_kernel<<<1, 1024, 0, stream>>>(hist, row_ptr, row_fill);
    scatter_kernel<<<(E_TOT + 255) / 256, 256, 0, stream>>>(ei, row_fill, ssrc);
    bounds_kernel<<<(N_NODES + 255) / 256, 256, 0, stream>>>(batch, gstart);

    // Layer 1
    {
        dim3 g((N_NODES + 127) / 128, H1C / 128);
        sgemm_h_kernel<<<g, 256, 0, stream>>>(x, W1, h1h, N_NODES, H1C, IN_C);
    }
    att1_kernel<<<N_NODES / 4, 256, 0, stream>>>(h1h, att_s1, att_d1, a_src1, a_dst1);
    edge1_kernel<<<N_NODES / 4, 256, 0, stream>>>(row_ptr, ssrc, h1h, a_src1, a_dst1, bias1, out1);

    // Layer 2
    {
        dim3 g((N_NODES + 127) / 128, OUT_C / 128);
        sgemm_h_kernel<<<g, 256, 0, stream>>>(out1, W2, h2h, N_NODES, OUT_C, H1C);
    }
    att2_kernel<<<N_NODES / 4, 256, 0, stream>>>(h2h, att_s2, att_d2, a_src2, a_dst2);
    edge2_kernel<<<N_NODES / 4, 256, 0, stream>>>(row_ptr, ssrc, h2h, a_src2, a_dst2, bias2, out2);

    // Pooling
    pool_kernel<<<(N_NODES + 127) / 128, 128, 0, stream>>>(out2, batch, d_out);
    final_kernel<<<(N_GRAPHS * 128 + 255) / 256, 256, 0, stream>>>(d_out, gstart);
}

// Round 7
// 521.703 us; speedup vs baseline: 1.7169x; 1.1686x over previous
//
#include <hip/hip_runtime.h>
#include <hip/hip_bf16.h>
#include <hip/hip_fp16.h>

// Problem constants (fixed by the reference setup)
#define N_NODES 50000
#define N_EDGES 800000
#define E_TOT   (N_EDGES + N_NODES)   // 850000 (self-loops appended)
#define IN_C    256
#define H1C     256                    // HEADS * HID_C = 4*64
#define HEADS   4
#define HID_C   64
#define OUT_C   128
#define N_GRAPHS 100
#define NEG_SLOPE 0.2f
#define EPS_F 1e-16f
#define SCAN_BLOCKS 196               // ceil(N_NODES / 256)

// ---------------------------------------------------------------------------
// CSR build: histogram -> 3-phase multi-block scan -> scatter
// (round-6 profile: single-block scan_kernel was 112 us at 0.14% occupancy)
// ---------------------------------------------------------------------------
__global__ void hist_kernel(const int* __restrict__ ei, int* __restrict__ hist) {
    int idx = blockIdx.x * 256 + threadIdx.x;
    if (idx < N_EDGES) {
        int d = ei[N_EDGES + idx];                // dst row
        if (d >= 0 && d < N_NODES) atomicAdd(&hist[d], 1);
    } else if (idx < E_TOT) {
        atomicAdd(&hist[idx - N_EDGES], 1);       // self loop
    }
}

__global__ __launch_bounds__(256) void scan_phase1(const int* __restrict__ hist,
                                                   int* __restrict__ blockSums) {
    __shared__ int lds[256];
    int idx = blockIdx.x * 256 + threadIdx.x;
    int v = (idx < N_NODES) ? hist[idx] : 0;
    lds[threadIdx.x] = v;
    __syncthreads();
#pragma unroll
    for (int off = 128; off > 0; off >>= 1) {
        if (threadIdx.x < off) lds[threadIdx.x] += lds[threadIdx.x + off];
        __syncthreads();
    }
    if (threadIdx.x == 0) blockSums[blockIdx.x] = lds[0];
}

__global__ __launch_bounds__(256) void scan_phase2(const int* __restrict__ blockSums,
                                                   int* __restrict__ blockOffsets) {
    __shared__ int lds[256];
    int t = threadIdx.x;
    int v = (t < SCAN_BLOCKS) ? blockSums[t] : 0;
    lds[t] = v;
    __syncthreads();
#pragma unroll
    for (int off = 1; off < 256; off <<= 1) {
        int u = (t >= off) ? lds[t - off] : 0;
        __syncthreads();
        lds[t] += u;
        __syncthreads();
    }
    if (t < SCAN_BLOCKS) blockOffsets[t] = lds[t] - v;   // exclusive offsets
    if (t == 255) blockOffsets[SCAN_BLOCKS] = lds[255];  // grand total
}

__global__ __launch_bounds__(256) void scan_phase3(const int* __restrict__ hist,
                                                   const int* __restrict__ blockOffsets,
                                                   int* __restrict__ row_ptr,
                                                   int* __restrict__ row_fill) {
    __shared__ int lds[256];
    int idx = blockIdx.x * 256 + threadIdx.x;
    int t = threadIdx.x;
    int v = (idx < N_NODES) ? hist[idx] : 0;
    lds[t] = v;
    __syncthreads();
#pragma unroll
    for (int off = 1; off < 256; off <<= 1) {
        int u = (t >= off) ? lds[t - off] : 0;
        __syncthreads();
        lds[t] += u;
        __syncthreads();
    }
    int excl = lds[t] - v + blockOffsets[blockIdx.x];
    if (idx < N_NODES) {
        row_ptr[idx] = excl;
        row_fill[idx] = excl;
    }
    if (idx == N_NODES - 1) row_ptr[N_NODES] = excl + v;
}

__global__ void scatter_kernel(const int* __restrict__ ei, int* __restrict__ row_fill,
                               int* __restrict__ ssrc) {
    int idx = blockIdx.x * 256 + threadIdx.x;
    if (idx < N_EDGES) {
        int s = ei[idx];
        int d = ei[N_EDGES + idx];
        if (s < 0 || s >= N_NODES || d < 0 || d >= N_NODES) return;  // defensive
        int pos = atomicAdd(&row_fill[d], 1);
        if (pos >= 0 && pos < E_TOT) ssrc[pos] = s;
    } else if (idx < E_TOT) {
        int nd = idx - N_EDGES;
        int pos = atomicAdd(&row_fill[nd], 1);
        if (pos >= 0 && pos < E_TOT) ssrc[pos] = nd;
    }
}

// ---------------------------------------------------------------------------
// SGEMM with fp16 output: C[M,N] = fp16(A[M,K] * B[K,N])
// fp32 accumulate, 128x128 tile, 8x8 per thread.
// ---------------------------------------------------------------------------
__global__ __launch_bounds__(256) void sgemm_h_kernel(const float* __restrict__ A,
                                                      const float* __restrict__ B,
                                                      __half* __restrict__ C,
                                                      int M, int N, int K) {
    __shared__ __align__(16) float As[8][132];
    __shared__ __align__(16) float Bs[8][132];
    const int tid = threadIdx.x;
    const int tileM = blockIdx.x * 128;
    const int tileN = blockIdx.y * 128;
    const int tx = tid & 15, ty = tid >> 4;

    float acc[8][8] = {};

    const int mA = tid >> 1;              // 0..127
    const int kA = (tid & 1) * 4;         // 0 or 4
    const int rowA = tileM + mA;
    const bool rowAok = rowA < M;
    const float* Aptr = A + (size_t)rowA * K + kA;

    const int kB = tid >> 5;              // 0..7
    const int nB = (tid & 31) * 4;        // 0..124
    const float* Bptr = B + (size_t)kB * N + tileN + nB;

    for (int kk = 0; kk < K; kk += 8) {
        float4 av = make_float4(0.f, 0.f, 0.f, 0.f);
        if (rowAok) av = *reinterpret_cast<const float4*>(Aptr + kk);
        float4 bv = *reinterpret_cast<const float4*>(Bptr + (size_t)kk * N);
        __syncthreads();
        As[kA + 0][mA] = av.x;
        As[kA + 1][mA] = av.y;
        As[kA + 2][mA] = av.z;
        As[kA + 3][mA] = av.w;
        *reinterpret_cast<float4*>(&Bs[kB][nB]) = bv;
        __syncthreads();
#pragma unroll
        for (int k = 0; k < 8; ++k) {
            float4 a0 = *reinterpret_cast<const float4*>(&As[k][ty * 8]);
            float4 a1 = *reinterpret_cast<const float4*>(&As[k][ty * 8 + 4]);
            float4 b0 = *reinterpret_cast<const float4*>(&Bs[k][tx * 8]);
            float4 b1 = *reinterpret_cast<const float4*>(&Bs[k][tx * 8 + 4]);
            float a[8] = {a0.x, a0.y, a0.z, a0.w, a1.x, a1.y, a1.z, a1.w};
            float b[8] = {b0.x, b0.y, b0.z, b0.w, b1.x, b1.y, b1.z, b1.w};
#pragma unroll
            for (int i = 0; i < 8; ++i)
#pragma unroll
                for (int j = 0; j < 8; ++j)
                    acc[i][j] += a[i] * b[j];
        }
    }
#pragma unroll
    for (int i = 0; i < 8; ++i) {
        int row = tileM + ty * 8 + i;
        if (row < M) {
            union { __half h[8]; uint4 u; } cv;
#pragma unroll
            for (int j = 0; j < 8; ++j) cv.h[j] = __float2half(acc[i][j]);
            *reinterpret_cast<uint4*>(C + (size_t)row * N + tileN + tx * 8) = cv.u;
        }
    }
}

// ---------------------------------------------------------------------------
// Attention score dots (fp16 h, fp32 math)
// ---------------------------------------------------------------------------
__global__ __launch_bounds__(256) void att1_kernel(const __half* __restrict__ h1h,
                                                   const float* __restrict__ att_src,
                                                   const float* __restrict__ att_dst,
                                                   float* __restrict__ a_src_o,
                                                   float* __restrict__ a_dst_o) {
    int node = blockIdx.x * 4 + (threadIdx.x >> 6);
    int lane = threadIdx.x & 63;
    uint2 raw = reinterpret_cast<const uint2*>(h1h)[(size_t)node * 64 + lane];
    float2 f01 = __half22float2(*reinterpret_cast<const __half2*>(&raw.x));
    float2 f23 = __half22float2(*reinterpret_cast<const __half2*>(&raw.y));
    float4 as = reinterpret_cast<const float4*>(att_src)[lane];
    float4 ad = reinterpret_cast<const float4*>(att_dst)[lane];
    float ps = f01.x * as.x + f01.y * as.y + f23.x * as.z + f23.y * as.w;
    float pd = f01.x * ad.x + f01.y * ad.y + f23.x * ad.z + f23.y * ad.w;
#pragma unroll
    for (int off = 1; off < 16; off <<= 1) {
        ps += __shfl_xor(ps, off);
        pd += __shfl_xor(pd, off);
    }
    if ((lane & 15) == 0) {
        int hd = lane >> 4;
        a_src_o[node * 4 + hd] = ps;
        a_dst_o[node * 4 + hd] = pd;
    }
}

__global__ __launch_bounds__(256) void att2_kernel(const __half* __restrict__ h2h,
                                                   const float* __restrict__ att_src,
                                                   const float* __restrict__ att_dst,
                                                   float* __restrict__ a_src_o,
                                                   float* __restrict__ a_dst_o) {
    int node = blockIdx.x * 4 + (threadIdx.x >> 6);
    int lane = threadIdx.x & 63;
    __half2 raw = reinterpret_cast<const __half2*>(h2h)[(size_t)node * 64 + lane];
    float2 hv = __half22float2(raw);
    float2 as = reinterpret_cast<const float2*>(att_src)[lane];
    float2 ad = reinterpret_cast<const float2*>(att_dst)[lane];
    float ps = hv.x * as.x + hv.y * as.y;
    float pd = hv.x * ad.x + hv.y * ad.y;
#pragma unroll
    for (int off = 1; off < 64; off <<= 1) {
        ps += __shfl_xor(ps, off);
        pd += __shfl_xor(pd, off);
    }
    if (lane == 0) {
        a_src_o[node] = ps;
        a_dst_o[node] = pd;
    }
}

__device__ __forceinline__ float lrelu(float x) { return x > 0.f ? x : NEG_SLOPE * x; }

// ---------------------------------------------------------------------------
// Edge aggregation, layer 1: one wave per destination node, 4 heads x 64 ch.
// fp16 gather payload (8 B/lane), fp32 accumulate, 4-way unrolled.
// ---------------------------------------------------------------------------
__global__ __launch_bounds__(256) void edge1_kernel(const int* __restrict__ row_ptr,
                                                    const int* __restrict__ ssrc,
                                                    const __half* __restrict__ h1h,
                                                    const float* __restrict__ a_src,
                                                    const float* __restrict__ a_dst,
                                                    const float* __restrict__ bias,
                                                    float* __restrict__ out) {
    int node = blockIdx.x * 4 + (threadIdx.x >> 6);
    int lane = threadIdx.x & 63;
    int start = row_ptr[node], end = row_ptr[node + 1];
    float ad0 = a_dst[node * 4 + 0];
    float ad1 = a_dst[node * 4 + 1];
    float ad2 = a_dst[node * 4 + 2];
    float ad3 = a_dst[node * 4 + 3];

    // Phase A: softmax denominator per head (max-shift skipped: alphas are O(1))
    float s0 = 0.f, s1 = 0.f, s2 = 0.f, s3 = 0.f;
    for (int e = start + lane; e < end; e += 64) {
        int si = ssrc[e];
        float4 av = reinterpret_cast<const float4*>(a_src)[si];
        s0 += __expf(lrelu(av.x + ad0));
        s1 += __expf(lrelu(av.y + ad1));
        s2 += __expf(lrelu(av.z + ad2));
        s3 += __expf(lrelu(av.w + ad3));
    }
#pragma unroll
    for (int off = 1; off < 64; off <<= 1) {
        s0 += __shfl_xor(s0, off);
        s1 += __shfl_xor(s1, off);
        s2 += __shfl_xor(s2, off);
        s3 += __shfl_xor(s3, off);
    }
    int hd = lane >> 4;
    float Ssel = hd == 0 ? s0 : hd == 1 ? s1 : hd == 2 ? s2 : s3;
    float adh  = hd == 0 ? ad0 : hd == 1 ? ad1 : hd == 2 ? ad2 : ad3;
    float inv = 1.0f / (Ssel + EPS_F);

    // Phase B: weighted gather-accumulate; lane holds flat channels lane*4..+3
    const uint2* h1v = reinterpret_cast<const uint2*>(h1h);
    float4 acc0 = make_float4(0.f, 0.f, 0.f, 0.f);
    float4 acc1 = make_float4(0.f, 0.f, 0.f, 0.f);
    float4 acc2 = make_float4(0.f, 0.f, 0.f, 0.f);
    float4 acc3 = make_float4(0.f, 0.f, 0.f, 0.f);
    int e = start;
    for (; e + 4 <= end; e += 4) {
        int si0 = ssrc[e + 0];
        int si1 = ssrc[e + 1];
        int si2 = ssrc[e + 2];
        int si3 = ssrc[e + 3];
        float r0 = a_src[si0 * 4 + hd];
        float r1 = a_src[si1 * 4 + hd];
        float r2 = a_src[si2 * 4 + hd];
        float r3 = a_src[si3 * 4 + hd];
        uint2 q0 = h1v[(size_t)si0 * 64 + lane];
        uint2 q1 = h1v[(size_t)si1 * 64 + lane];
        uint2 q2 = h1v[(size_t)si2 * 64 + lane];
        uint2 q3 = h1v[(size_t)si3 * 64 + lane];
        float w0 = __expf(lrelu(r0 + adh)) * inv;
        float w1 = __expf(lrelu(r1 + adh)) * inv;
        float w2 = __expf(lrelu(r2 + adh)) * inv;
        float w3 = __expf(lrelu(r3 + adh)) * inv;
        float2 f0a = __half22float2(*reinterpret_cast<const __half2*>(&q0.x));
        float2 f0b = __half22float2(*reinterpret_cast<const __half2*>(&q0.y));
        float2 f1a = __half22float2(*reinterpret_cast<const __half2*>(&q1.x));
        float2 f1b = __half22float2(*reinterpret_cast<const __half2*>(&q1.y));
        float2 f2a = __half22float2(*reinterpret_cast<const __half2*>(&q2.x));
        float2 f2b = __half22float2(*reinterpret_cast<const __half2*>(&q2.y));
        float2 f3a = __half22float2(*reinterpret_cast<const __half2*>(&q3.x));
        float2 f3b = __half22float2(*reinterpret_cast<const __half2*>(&q3.y));
        acc0.x += w0 * f0a.x; acc0.y += w0 * f0a.y; acc0.z += w0 * f0b.x; acc0.w += w0 * f0b.y;
        acc1.x += w1 * f1a.x; acc1.y += w1 * f1a.y; acc1.z += w1 * f1b.x; acc1.w += w1 * f1b.y;
        acc2.x += w2 * f2a.x; acc2.y += w2 * f2a.y; acc2.z += w2 * f2b.x; acc2.w += w2 * f2b.y;
        acc3.x += w3 * f3a.x; acc3.y += w3 * f3a.y; acc3.z += w3 * f3b.x; acc3.w += w3 * f3b.y;
    }
    for (; e < end; ++e) {
        int si = ssrc[e];
        float w = __expf(lrelu(a_src[si * 4 + hd] + adh)) * inv;
        uint2 q = h1v[(size_t)si * 64 + lane];
        float2 fa = __half22float2(*reinterpret_cast<const __half2*>(&q.x));
        float2 fb = __half22float2(*reinterpret_cast<const __half2*>(&q.y));
        acc0.x += w * fa.x; acc0.y += w * fa.y; acc0.z += w * fb.x; acc0.w += w * fb.y;
    }
    float4 acc;
    acc.x = (acc0.x + acc1.x) + (acc2.x + acc3.x);
    acc.y = (acc0.y + acc1.y) + (acc2.y + acc3.y);
    acc.z = (acc0.z + acc1.z) + (acc2.z + acc3.z);
    acc.w = (acc0.w + acc1.w) + (acc2.w + acc3.w);
    float4 bv = reinterpret_cast<const float4*>(bias)[lane];
    acc.x = fmaxf(acc.x + bv.x, 0.f);
    acc.y = fmaxf(acc.y + bv.y, 0.f);
    acc.z = fmaxf(acc.z + bv.z, 0.f);
    acc.w = fmaxf(acc.w + bv.w, 0.f);
    reinterpret_cast<float4*>(out)[(size_t)node * 64 + lane] = acc;
}

// ---------------------------------------------------------------------------
// Edge aggregation, layer 2: one wave per destination node, 1 head x 128 ch.
// fp16 gather payload (4 B/lane), fp32 accumulate, 4-way unrolled.
// ---------------------------------------------------------------------------
__global__ __launch_bounds__(256) void edge2_kernel(const int* __restrict__ row_ptr,
                                                    const int* __restrict__ ssrc,
                                                    const __half* __restrict__ h2h,
                                                    const float* __restrict__ a_src,
                                                    const float* __restrict__ a_dst,
                                                    const float* __restrict__ bias,
                                                    float* __restrict__ out) {
    int node = blockIdx.x * 4 + (threadIdx.x >> 6);
    int lane = threadIdx.x & 63;
    int start = row_ptr[node], end = row_ptr[node + 1];
    float ad = a_dst[node];

    float s = 0.f;
    for (int e = start + lane; e < end; e += 64) {
        int si = ssrc[e];
        s += __expf(lrelu(a_src[si] + ad));
    }
#pragma unroll
    for (int off = 1; off < 64; off <<= 1) s += __shfl_xor(s, off);
    float inv = 1.0f / (s + EPS_F);

    const __half2* h2v = reinterpret_cast<const __half2*>(h2h);
    float2 acc0 = make_float2(0.f, 0.f);
    float2 acc1 = make_float2(0.f, 0.f);
    float2 acc2 = make_float2(0.f, 0.f);
    float2 acc3 = make_float2(0.f, 0.f);
    int e = start;
    for (; e + 4 <= end; e += 4) {
        int si0 = ssrc[e + 0];
        int si1 = ssrc[e + 1];
        int si2 = ssrc[e + 2];
        int si3 = ssrc[e + 3];
        float r0 = a_src[si0];
        float r1 = a_src[si1];
        float r2 = a_src[si2];
        float r3 = a_src[si3];
        __half2 q0 = h2v[(size_t)si0 * 64 + lane];
        __half2 q1 = h2v[(size_t)si1 * 64 + lane];
        __half2 q2 = h2v[(size_t)si2 * 64 + lane];
        __half2 q3 = h2v[(size_t)si3 * 64 + lane];
        float w0 = __expf(lrelu(r0 + ad)) * inv;
        float w1 = __expf(lrelu(r1 + ad)) * inv;
        float w2 = __expf(lrelu(r2 + ad)) * inv;
        float w3 = __expf(lrelu(r3 + ad)) * inv;
        float2 v0 = __half22float2(q0);
        float2 v1 = __half22float2(q1);
        float2 v2 = __half22float2(q2);
        float2 v3 = __half22float2(q3);
        acc0.x += w0 * v0.x; acc0.y += w0 * v0.y;
        acc1.x += w1 * v1.x; acc1.y += w1 * v1.y;
        acc2.x += w2 * v2.x; acc2.y += w2 * v2.y;
        acc3.x += w3 * v3.x; acc3.y += w3 * v3.y;
    }
    for (; e < end; ++e) {
        int si = ssrc[e];
        float w = __expf(lrelu(a_src[si] + ad)) * inv;
        float2 hv = __half22float2(h2v[(size_t)si * 64 + lane]);
        acc0.x += w * hv.x; acc0.y += w * hv.y;
    }
    float2 acc;
    acc.x = (acc0.x + acc1.x) + (acc2.x + acc3.x);
    acc.y = (acc0.y + acc1.y) + (acc2.y + acc3.y);
    float2 bv = reinterpret_cast<const float2*>(bias)[lane];
    acc.x = fmaxf(acc.x + bv.x, 0.f);
    acc.y = fmaxf(acc.y + bv.y, 0.f);
    reinterpret_cast<float2*>(out)[(size_t)node * 64 + lane] = acc;
}

// ---------------------------------------------------------------------------
// Pooling: batch is sorted -> per-block running accumulator, flush on change
// ---------------------------------------------------------------------------
__global__ __launch_bounds__(128) void pool_kernel(const float* __restrict__ out2,
                                                   const int* __restrict__ batch,
                                                   float* __restrict__ d_out) {
    int c = threadIdx.x;                 // channel 0..127
    int node0 = blockIdx.x * 128;
    int nodeEnd = node0 + 128; if (nodeEnd > N_NODES) nodeEnd = N_NODES;
    if (node0 >= N_NODES) return;
    int gprev = batch[node0];
    float acc = 0.f;
    for (int node = node0; node < nodeEnd; ++node) {
        int g = batch[node];
        if (g != gprev) {
            if (gprev >= 0 && gprev < N_GRAPHS) atomicAdd(&d_out[gprev * 128 + c], acc);
            acc = 0.f;
            gprev = g;
        }
        acc += out2[(size_t)node * 128 + c];
    }
    if (gprev >= 0 && gprev < N_GRAPHS) atomicAdd(&d_out[gprev * 128 + c], acc);
}

// Graph boundary detection: batch is sorted, so each graph's start index is
// written exactly once (no contended atomics).
__global__ void bounds_kernel(const int* __restrict__ batch, int* __restrict__ gstart) {
    int idx = blockIdx.x * 256 + threadIdx.x;
    if (idx >= N_NODES) return;
    int g = batch[idx];
    if (g < 0) g = 0; if (g >= N_GRAPHS) g = N_GRAPHS - 1;
    if (idx == 0) {
        for (int j = 0; j <= g; ++j) gstart[j] = 0;
    } else {
        int gp = batch[idx - 1];
        if (gp < 0) gp = 0; if (gp >= N_GRAPHS) gp = N_GRAPHS - 1;
        for (int j = gp + 1; j <= g; ++j) gstart[j] = idx;
    }
    if (idx == N_NODES - 1) {
        for (int j = g + 1; j <= N_GRAPHS; ++j) gstart[j] = N_NODES;
    }
}

__global__ void final_kernel(float* __restrict__ d_out, const int* __restrict__ gstart) {
    int idx = blockIdx.x * 256 + threadIdx.x;
    if (idx < N_GRAPHS * 128) {
        int g = idx >> 7;
        float c = (float)(gstart[g + 1] - gstart[g]);
        if (c < 1.f) c = 1.f;
        d_out[idx] = d_out[idx] / c;
    }
}

// ---------------------------------------------------------------------------
extern "C" void kernel_launch(void* const* d_in, const int* in_sizes, int n_in,
                              void* d_out_v, int out_size, void* d_ws, size_t ws_size,
                              hipStream_t stream) {
    const float* x      = (const float*)d_in[0];
    const float* W1     = (const float*)d_in[1];
    const float* att_s1 = (const float*)d_in[2];
    const float* att_d1 = (const float*)d_in[3];
    const float* bias1  = (const float*)d_in[4];
    const float* W2     = (const float*)d_in[5];
    const float* att_s2 = (const float*)d_in[6];
    const float* att_d2 = (const float*)d_in[7];
    const float* bias2  = (const float*)d_in[8];
    const int*   ei     = (const int*)d_in[9];
    const int*   batch  = (const int*)d_in[10];
    float* d_out = (float*)d_out_v;

    // Workspace layout (float units):
    //  [0, 12.8M)        out1 fp32 (layer-1 output)  ... later reused as out2
    //  [12.8M, 19.2M)    h1h fp16 (12.8M halfs)      ... later reused as h2h
    //  [19.2M, ...)      attention scalars + CSR ints
    float* ws = (float*)d_ws;
    float*  out1   = ws;                                 // 12.8M floats
    __half* h1h    = (__half*)(ws + 12800000);           // 12.8M halfs = 6.4M floats
    __half* h2h    = h1h;                                // 6.4M halfs (h1h dead by then)
    float*  out2   = ws;                                 // 6.4M floats (out1 dead by then)
    float* a_src1 = ws + 19200000;             // N*4
    float* a_dst1 = a_src1 + 200000;           // N*4
    float* a_src2 = a_dst1 + 200000;           // N
    float* a_dst2 = a_src2 + 50000;            // N
    int* hist     = (int*)(a_dst2 + 50000);    // N
    int* row_ptr  = hist + 50000;              // N+1 (padded to 50016)
    int* row_fill = row_ptr + 50016;           // N (padded to 50016)
    int* ssrc     = row_fill + 50016;          // E_TOT
    int* gstart   = ssrc + E_TOT;              // N_GRAPHS+1 (pad 128)
    int* blockSums    = gstart + 128;          // SCAN_BLOCKS
    int* blockOffsets = blockSums + SCAN_BLOCKS; // SCAN_BLOCKS+1

    // Zero what must be zero
    hipMemsetAsync(hist, 0, N_NODES * sizeof(int), stream);
    hipMemsetAsync(d_out, 0, N_GRAPHS * 128 * sizeof(float), stream);

    // CSR build
    hist_kernel<<<(E_TOT + 255) / 256, 256, 0, stream>>>(ei, hist);
    scan_phase1<<<SCAN_BLOCKS, 256, 0, stream>>>(hist, blockSums);
    scan_phase2<<<1, 256, 0, stream>>>(blockSums, blockOffsets);
    scan_phase3<<<SCAN_BLOCKS, 256, 0, stream>>>(hist, blockOffsets, row_ptr, row_fill);
    scatter_kernel<<<(E_TOT + 255) / 256, 256, 0, stream>>>(ei, row_fill, ssrc);
    bounds_kernel<<<(N_NODES + 255) / 256, 256, 0, stream>>>(batch, gstart);

    // Layer 1
    {
        dim3 g((N_NODES + 127) / 128, H1C / 128);
        sgemm_h_kernel<<<g, 256, 0, stream>>>(x, W1, h1h, N_NODES, H1C, IN_C);
    }
    att1_kernel<<<N_NODES / 4, 256, 0, stream>>>(h1h, att_s1, att_d1, a_src1, a_dst1);
    edge1_kernel<<<N_NODES / 4, 256, 0, stream>>>(row_ptr, ssrc, h1h, a_src1, a_dst1, bias1, out1);

    // Layer 2
    {
        dim3 g((N_NODES + 127) / 128, OUT_C / 128);
        sgemm_h_kernel<<<g, 256, 0, stream>>>(out1, W2, h2h, N_NODES, OUT_C, H1C);
    }
    att2_kernel<<<N_NODES / 4, 256, 0, stream>>>(h2h, att_s2, att_d2, a_src2, a_dst2);
    edge2_kernel<<<N_NODES / 4, 256, 0, stream>>>(row_ptr, ssrc, h2h, a_src2, a_dst2, bias2, out2);

    // Pooling
    pool_kernel<<<(N_NODES + 127) / 128, 128, 0, stream>>>(out2, batch, d_out);
    final_kernel<<<(N_GRAPHS * 128 + 255) / 256, 256, 0, stream>>>(d_out, gstart);
}

// Round 8
// 420.378 us; speedup vs baseline: 2.1308x; 1.2410x over previous
//
#include <hip/hip_runtime.h>
#include <hip/hip_bf16.h>
#include <hip/hip_fp16.h>

// Problem constants (fixed by the reference setup)
#define N_NODES 50000
#define N_EDGES 800000
#define E_TOT   (N_EDGES + N_NODES)   // 850000 (self-loops appended)
#define IN_C    256
#define H1C     256                    // HEADS * HID_C = 4*64
#define HEADS   4
#define HID_C   64
#define OUT_C   128
#define N_GRAPHS 100
#define NEG_SLOPE 0.2f
#define EPS_F 1e-16f
#define SCAN_BLOCKS 196               // ceil(N_NODES / 256)

typedef _Float16 half8_t __attribute__((ext_vector_type(8)));
typedef float f32x4 __attribute__((ext_vector_type(4)));

// ---------------------------------------------------------------------------
// CSR build: histogram -> 3-phase multi-block scan -> scatter
// ---------------------------------------------------------------------------
__global__ void hist_kernel(const int* __restrict__ ei, int* __restrict__ hist) {
    int idx = blockIdx.x * 256 + threadIdx.x;
    if (idx < N_EDGES) {
        int d = ei[N_EDGES + idx];                // dst row
        if (d >= 0 && d < N_NODES) atomicAdd(&hist[d], 1);
    } else if (idx < E_TOT) {
        atomicAdd(&hist[idx - N_EDGES], 1);       // self loop
    }
}

__global__ __launch_bounds__(256) void scan_phase1(const int* __restrict__ hist,
                                                   int* __restrict__ blockSums) {
    __shared__ int lds[256];
    int idx = blockIdx.x * 256 + threadIdx.x;
    int v = (idx < N_NODES) ? hist[idx] : 0;
    lds[threadIdx.x] = v;
    __syncthreads();
#pragma unroll
    for (int off = 128; off > 0; off >>= 1) {
        if (threadIdx.x < off) lds[threadIdx.x] += lds[threadIdx.x + off];
        __syncthreads();
    }
    if (threadIdx.x == 0) blockSums[blockIdx.x] = lds[0];
}

__global__ __launch_bounds__(256) void scan_phase2(const int* __restrict__ blockSums,
                                                   int* __restrict__ blockOffsets) {
    __shared__ int lds[256];
    int t = threadIdx.x;
    int v = (t < SCAN_BLOCKS) ? blockSums[t] : 0;
    lds[t] = v;
    __syncthreads();
#pragma unroll
    for (int off = 1; off < 256; off <<= 1) {
        int u = (t >= off) ? lds[t - off] : 0;
        __syncthreads();
        lds[t] += u;
        __syncthreads();
    }
    if (t < SCAN_BLOCKS) blockOffsets[t] = lds[t] - v;   // exclusive offsets
    if (t == 255) blockOffsets[SCAN_BLOCKS] = lds[255];  // grand total
}

__global__ __launch_bounds__(256) void scan_phase3(const int* __restrict__ hist,
                                                   const int* __restrict__ blockOffsets,
                                                   int* __restrict__ row_ptr,
                                                   int* __restrict__ row_fill) {
    __shared__ int lds[256];
    int idx = blockIdx.x * 256 + threadIdx.x;
    int t = threadIdx.x;
    int v = (idx < N_NODES) ? hist[idx] : 0;
    lds[t] = v;
    __syncthreads();
#pragma unroll
    for (int off = 1; off < 256; off <<= 1) {
        int u = (t >= off) ? lds[t - off] : 0;
        __syncthreads();
        lds[t] += u;
        __syncthreads();
    }
    int excl = lds[t] - v + blockOffsets[blockIdx.x];
    if (idx < N_NODES) {
        row_ptr[idx] = excl;
        row_fill[idx] = excl;
    }
    if (idx == N_NODES - 1) row_ptr[N_NODES] = excl + v;
}

__global__ void scatter_kernel(const int* __restrict__ ei, int* __restrict__ row_fill,
                               int* __restrict__ ssrc) {
    int idx = blockIdx.x * 256 + threadIdx.x;
    if (idx < N_EDGES) {
        int s = ei[idx];
        int d = ei[N_EDGES + idx];
        if (s < 0 || s >= N_NODES || d < 0 || d >= N_NODES) return;  // defensive
        int pos = atomicAdd(&row_fill[d], 1);
        if (pos >= 0 && pos < E_TOT) ssrc[pos] = s;
    } else if (idx < E_TOT) {
        int nd = idx - N_EDGES;
        int pos = atomicAdd(&row_fill[nd], 1);
        if (pos >= 0 && pos < E_TOT) ssrc[pos] = nd;
    }
}

// ---------------------------------------------------------------------------
// Precision prep: cast x fp32->fp16; transpose W (K=256 rows) to [N][K] fp16
// ---------------------------------------------------------------------------
__global__ void cast_x_kernel(const float* __restrict__ x, _Float16* __restrict__ xh,
                              int n4) {
    int idx = blockIdx.x * 256 + threadIdx.x;
    if (idx < n4) {
        float4 v = reinterpret_cast<const float4*>(x)[idx];
        union { _Float16 h[4]; uint2 u; } p;
        p.h[0] = (_Float16)v.x; p.h[1] = (_Float16)v.y;
        p.h[2] = (_Float16)v.z; p.h[3] = (_Float16)v.w;
        reinterpret_cast<uint2*>(xh)[idx] = p.u;
    }
}

__global__ void transpose_w_kernel(const float* __restrict__ W, _Float16* __restrict__ Wt,
                                   int KN, int N) {
    // W [256][N] -> Wt [N][256]; idx indexes Wt flat (write-coalesced)
    int idx = blockIdx.x * 256 + threadIdx.x;
    if (idx < KN) {
        int n = idx >> 8, k = idx & 255;
        Wt[idx] = (_Float16)W[k * N + n];
    }
}

// ---------------------------------------------------------------------------
// MFMA fp16 GEMM: C[M,N] = fp16( A[M,256] * Bt[N,256]^T ), fp32 accumulate.
// 128x128 block tile, 4 waves each computing 64x64 via 4x4 mfma_16x16x32_f16.
// Fragment layouts (guide-verified): A: m=lane&15, k=quad*8+j;
// B (from B^T rows): n=lane&15, k=quad*8+j; C/D: row=quad*4+reg, col=lane&15.
// ---------------------------------------------------------------------------
__global__ __launch_bounds__(256) void gemm_mfma_kernel(const _Float16* __restrict__ A,
                                                        const _Float16* __restrict__ Bt,
                                                        _Float16* __restrict__ C,
                                                        int M, int N) {
    __shared__ _Float16 As[128][48];   // ldk=48 keeps 16B alignment everywhere
    __shared__ _Float16 Bs[128][48];
    const int tid = threadIdx.x;
    const int tileM = blockIdx.x * 128;
    const int tileN = blockIdx.y * 128;
    const int w = tid >> 6, lane = tid & 63;
    const int wm = (w >> 1) * 64, wn = (w & 1) * 64;
    const int quad = lane >> 4, mlane = lane & 15;
    const int srow = tid >> 2;           // 0..63 (rows srow and srow+64)
    const int schunk = (tid & 3) * 8;    // f16 offset within 32-k slab

    f32x4 zero = {0.f, 0.f, 0.f, 0.f};
    f32x4 acc[4][4];
#pragma unroll
    for (int i = 0; i < 4; ++i)
#pragma unroll
        for (int j = 0; j < 4; ++j) acc[i][j] = zero;

    const uint4* Av = reinterpret_cast<const uint4*>(A);   // 8 f16 per uint4; 32/row
    const uint4* Bv = reinterpret_cast<const uint4*>(Bt);
    const int r0 = tileM + srow, r1 = r0 + 64;
    const bool ok0 = r0 < M, ok1 = r1 < M;
    const int bn0 = tileN + srow, bn1 = bn0 + 64;          // N mult of 128: no guard
    const uint4 z4 = make_uint4(0, 0, 0, 0);

    for (int k0 = 0; k0 < 256; k0 += 32) {
        const int kc = (k0 >> 3) + (tid & 3);
        uint4 a0 = ok0 ? Av[(size_t)r0 * 32 + kc] : z4;
        uint4 a1 = ok1 ? Av[(size_t)r1 * 32 + kc] : z4;
        uint4 b0 = Bv[(size_t)bn0 * 32 + kc];
        uint4 b1 = Bv[(size_t)bn1 * 32 + kc];
        __syncthreads();
        *reinterpret_cast<uint4*>(&As[srow][schunk]) = a0;
        *reinterpret_cast<uint4*>(&As[srow + 64][schunk]) = a1;
        *reinterpret_cast<uint4*>(&Bs[srow][schunk]) = b0;
        *reinterpret_cast<uint4*>(&Bs[srow + 64][schunk]) = b1;
        __syncthreads();
        half8_t af[4], bf[4];
#pragma unroll
        for (int mt = 0; mt < 4; ++mt)
            af[mt] = *reinterpret_cast<const half8_t*>(&As[wm + mt * 16 + mlane][quad * 8]);
#pragma unroll
        for (int nt = 0; nt < 4; ++nt)
            bf[nt] = *reinterpret_cast<const half8_t*>(&Bs[wn + nt * 16 + mlane][quad * 8]);
#pragma unroll
        for (int mt = 0; mt < 4; ++mt)
#pragma unroll
            for (int nt = 0; nt < 4; ++nt)
                acc[mt][nt] = __builtin_amdgcn_mfma_f32_16x16x32_f16(af[mt], bf[nt], acc[mt][nt], 0, 0, 0);
    }
#pragma unroll
    for (int mt = 0; mt < 4; ++mt) {
#pragma unroll
        for (int i = 0; i < 4; ++i) {
            int row = tileM + wm + mt * 16 + quad * 4 + i;
            if (row < M) {
                _Float16* cp = C + (size_t)row * N + tileN + wn;
#pragma unroll
                for (int nt = 0; nt < 4; ++nt)
                    cp[nt * 16 + mlane] = (_Float16)acc[mt][nt][i];
            }
        }
    }
}

// ---------------------------------------------------------------------------
// Attention score dots (fp16 h, fp32 math)
// ---------------------------------------------------------------------------
__global__ __launch_bounds__(256) void att1_kernel(const __half* __restrict__ h1h,
                                                   const float* __restrict__ att_src,
                                                   const float* __restrict__ att_dst,
                                                   float* __restrict__ a_src_o,
                                                   float* __restrict__ a_dst_o) {
    int node = blockIdx.x * 4 + (threadIdx.x >> 6);
    int lane = threadIdx.x & 63;
    uint2 raw = reinterpret_cast<const uint2*>(h1h)[(size_t)node * 64 + lane];
    float2 f01 = __half22float2(*reinterpret_cast<const __half2*>(&raw.x));
    float2 f23 = __half22float2(*reinterpret_cast<const __half2*>(&raw.y));
    float4 as = reinterpret_cast<const float4*>(att_src)[lane];
    float4 ad = reinterpret_cast<const float4*>(att_dst)[lane];
    float ps = f01.x * as.x + f01.y * as.y + f23.x * as.z + f23.y * as.w;
    float pd = f01.x * ad.x + f01.y * ad.y + f23.x * ad.z + f23.y * ad.w;
#pragma unroll
    for (int off = 1; off < 16; off <<= 1) {
        ps += __shfl_xor(ps, off);
        pd += __shfl_xor(pd, off);
    }
    if ((lane & 15) == 0) {
        int hd = lane >> 4;
        a_src_o[node * 4 + hd] = ps;
        a_dst_o[node * 4 + hd] = pd;
    }
}

__global__ __launch_bounds__(256) void att2_kernel(const __half* __restrict__ h2h,
                                                   const float* __restrict__ att_src,
                                                   const float* __restrict__ att_dst,
                                                   float* __restrict__ a_src_o,
                                                   float* __restrict__ a_dst_o) {
    int node = blockIdx.x * 4 + (threadIdx.x >> 6);
    int lane = threadIdx.x & 63;
    __half2 raw = reinterpret_cast<const __half2*>(h2h)[(size_t)node * 64 + lane];
    float2 hv = __half22float2(raw);
    float2 as = reinterpret_cast<const float2*>(att_src)[lane];
    float2 ad = reinterpret_cast<const float2*>(att_dst)[lane];
    float ps = hv.x * as.x + hv.y * as.y;
    float pd = hv.x * ad.x + hv.y * ad.y;
#pragma unroll
    for (int off = 1; off < 64; off <<= 1) {
        ps += __shfl_xor(ps, off);
        pd += __shfl_xor(pd, off);
    }
    if (lane == 0) {
        a_src_o[node] = ps;
        a_dst_o[node] = pd;
    }
}

__device__ __forceinline__ float lrelu(float x) { return x > 0.f ? x : NEG_SLOPE * x; }

// ---------------------------------------------------------------------------
// Edge aggregation, layer 1: one wave per destination node, 4 heads x 64 ch.
// fp16 gather payload, fp32 accumulate, 4-way unrolled. fp16 OUTPUT (feeds
// the layer-2 MFMA GEMM directly and halves write traffic).
// ---------------------------------------------------------------------------
__global__ __launch_bounds__(256) void edge1_kernel(const int* __restrict__ row_ptr,
                                                    const int* __restrict__ ssrc,
                                                    const __half* __restrict__ h1h,
                                                    const float* __restrict__ a_src,
                                                    const float* __restrict__ a_dst,
                                                    const float* __restrict__ bias,
                                                    __half* __restrict__ out) {
    int node = blockIdx.x * 4 + (threadIdx.x >> 6);
    int lane = threadIdx.x & 63;
    int start = row_ptr[node], end = row_ptr[node + 1];
    float ad0 = a_dst[node * 4 + 0];
    float ad1 = a_dst[node * 4 + 1];
    float ad2 = a_dst[node * 4 + 2];
    float ad3 = a_dst[node * 4 + 3];

    // Phase A: softmax denominator per head (max-shift skipped: alphas are O(1))
    float s0 = 0.f, s1 = 0.f, s2 = 0.f, s3 = 0.f;
    for (int e = start + lane; e < end; e += 64) {
        int si = ssrc[e];
        float4 av = reinterpret_cast<const float4*>(a_src)[si];
        s0 += __expf(lrelu(av.x + ad0));
        s1 += __expf(lrelu(av.y + ad1));
        s2 += __expf(lrelu(av.z + ad2));
        s3 += __expf(lrelu(av.w + ad3));
    }
#pragma unroll
    for (int off = 1; off < 64; off <<= 1) {
        s0 += __shfl_xor(s0, off);
        s1 += __shfl_xor(s1, off);
        s2 += __shfl_xor(s2, off);
        s3 += __shfl_xor(s3, off);
    }
    int hd = lane >> 4;
    float Ssel = hd == 0 ? s0 : hd == 1 ? s1 : hd == 2 ? s2 : s3;
    float adh  = hd == 0 ? ad0 : hd == 1 ? ad1 : hd == 2 ? ad2 : ad3;
    float inv = 1.0f / (Ssel + EPS_F);

    // Phase B: weighted gather-accumulate; lane holds flat channels lane*4..+3
    const uint2* h1v = reinterpret_cast<const uint2*>(h1h);
    float4 acc0 = make_float4(0.f, 0.f, 0.f, 0.f);
    float4 acc1 = make_float4(0.f, 0.f, 0.f, 0.f);
    float4 acc2 = make_float4(0.f, 0.f, 0.f, 0.f);
    float4 acc3 = make_float4(0.f, 0.f, 0.f, 0.f);
    int e = start;
    for (; e + 4 <= end; e += 4) {
        int si0 = ssrc[e + 0];
        int si1 = ssrc[e + 1];
        int si2 = ssrc[e + 2];
        int si3 = ssrc[e + 3];
        float r0 = a_src[si0 * 4 + hd];
        float r1 = a_src[si1 * 4 + hd];
        float r2 = a_src[si2 * 4 + hd];
        float r3 = a_src[si3 * 4 + hd];
        uint2 q0 = h1v[(size_t)si0 * 64 + lane];
        uint2 q1 = h1v[(size_t)si1 * 64 + lane];
        uint2 q2 = h1v[(size_t)si2 * 64 + lane];
        uint2 q3 = h1v[(size_t)si3 * 64 + lane];
        float w0 = __expf(lrelu(r0 + adh)) * inv;
        float w1 = __expf(lrelu(r1 + adh)) * inv;
        float w2 = __expf(lrelu(r2 + adh)) * inv;
        float w3 = __expf(lrelu(r3 + adh)) * inv;
        float2 f0a = __half22float2(*reinterpret_cast<const __half2*>(&q0.x));
        float2 f0b = __half22float2(*reinterpret_cast<const __half2*>(&q0.y));
        float2 f1a = __half22float2(*reinterpret_cast<const __half2*>(&q1.x));
        float2 f1b = __half22float2(*reinterpret_cast<const __half2*>(&q1.y));
        float2 f2a = __half22float2(*reinterpret_cast<const __half2*>(&q2.x));
        float2 f2b = __half22float2(*reinterpret_cast<const __half2*>(&q2.y));
        float2 f3a = __half22float2(*reinterpret_cast<const __half2*>(&q3.x));
        float2 f3b = __half22float2(*reinterpret_cast<const __half2*>(&q3.y));
        acc0.x += w0 * f0a.x; acc0.y += w0 * f0a.y; acc0.z += w0 * f0b.x; acc0.w += w0 * f0b.y;
        acc1.x += w1 * f1a.x; acc1.y += w1 * f1a.y; acc1.z += w1 * f1b.x; acc1.w += w1 * f1b.y;
        acc2.x += w2 * f2a.x; acc2.y += w2 * f2a.y; acc2.z += w2 * f2b.x; acc2.w += w2 * f2b.y;
        acc3.x += w3 * f3a.x; acc3.y += w3 * f3a.y; acc3.z += w3 * f3b.x; acc3.w += w3 * f3b.y;
    }
    for (; e < end; ++e) {
        int si = ssrc[e];
        float w = __expf(lrelu(a_src[si * 4 + hd] + adh)) * inv;
        uint2 q = h1v[(size_t)si * 64 + lane];
        float2 fa = __half22float2(*reinterpret_cast<const __half2*>(&q.x));
        float2 fb = __half22float2(*reinterpret_cast<const __half2*>(&q.y));
        acc0.x += w * fa.x; acc0.y += w * fa.y; acc0.z += w * fb.x; acc0.w += w * fb.y;
    }
    float4 acc;
    acc.x = (acc0.x + acc1.x) + (acc2.x + acc3.x);
    acc.y = (acc0.y + acc1.y) + (acc2.y + acc3.y);
    acc.z = (acc0.z + acc1.z) + (acc2.z + acc3.z);
    acc.w = (acc0.w + acc1.w) + (acc2.w + acc3.w);
    float4 bv = reinterpret_cast<const float4*>(bias)[lane];
    union { __half h[4]; uint2 u; } st;
    st.h[0] = __float2half(fmaxf(acc.x + bv.x, 0.f));
    st.h[1] = __float2half(fmaxf(acc.y + bv.y, 0.f));
    st.h[2] = __float2half(fmaxf(acc.z + bv.z, 0.f));
    st.h[3] = __float2half(fmaxf(acc.w + bv.w, 0.f));
    reinterpret_cast<uint2*>(out)[(size_t)node * 64 + lane] = st.u;
}

// ---------------------------------------------------------------------------
// Edge aggregation, layer 2: one wave per destination node, 1 head x 128 ch.
// fp16 gather payload, fp32 accumulate + fp32 output (pool input).
// ---------------------------------------------------------------------------
__global__ __launch_bounds__(256) void edge2_kernel(const int* __restrict__ row_ptr,
                                                    const int* __restrict__ ssrc,
                                                    const __half* __restrict__ h2h,
                                                    const float* __restrict__ a_src,
                                                    const float* __restrict__ a_dst,
                                                    const float* __restrict__ bias,
                                                    float* __restrict__ out) {
    int node = blockIdx.x * 4 + (threadIdx.x >> 6);
    int lane = threadIdx.x & 63;
    int start = row_ptr[node], end = row_ptr[node + 1];
    float ad = a_dst[node];

    float s = 0.f;
    for (int e = start + lane; e < end; e += 64) {
        int si = ssrc[e];
        s += __expf(lrelu(a_src[si] + ad));
    }
#pragma unroll
    for (int off = 1; off < 64; off <<= 1) s += __shfl_xor(s, off);
    float inv = 1.0f / (s + EPS_F);

    const __half2* h2v = reinterpret_cast<const __half2*>(h2h);
    float2 acc0 = make_float2(0.f, 0.f);
    float2 acc1 = make_float2(0.f, 0.f);
    float2 acc2 = make_float2(0.f, 0.f);
    float2 acc3 = make_float2(0.f, 0.f);
    int e = start;
    for (; e + 4 <= end; e += 4) {
        int si0 = ssrc[e + 0];
        int si1 = ssrc[e + 1];
        int si2 = ssrc[e + 2];
        int si3 = ssrc[e + 3];
        float r0 = a_src[si0];
        float r1 = a_src[si1];
        float r2 = a_src[si2];
        float r3 = a_src[si3];
        __half2 q0 = h2v[(size_t)si0 * 64 + lane];
        __half2 q1 = h2v[(size_t)si1 * 64 + lane];
        __half2 q2 = h2v[(size_t)si2 * 64 + lane];
        __half2 q3 = h2v[(size_t)si3 * 64 + lane];
        float w0 = __expf(lrelu(r0 + ad)) * inv;
        float w1 = __expf(lrelu(r1 + ad)) * inv;
        float w2 = __expf(lrelu(r2 + ad)) * inv;
        float w3 = __expf(lrelu(r3 + ad)) * inv;
        float2 v0 = __half22float2(q0);
        float2 v1 = __half22float2(q1);
        float2 v2 = __half22float2(q2);
        float2 v3 = __half22float2(q3);
        acc0.x += w0 * v0.x; acc0.y += w0 * v0.y;
        acc1.x += w1 * v1.x; acc1.y += w1 * v1.y;
        acc2.x += w2 * v2.x; acc2.y += w2 * v2.y;
        acc3.x += w3 * v3.x; acc3.y += w3 * v3.y;
    }
    for (; e < end; ++e) {
        int si = ssrc[e];
        float w = __expf(lrelu(a_src[si] + ad)) * inv;
        float2 hv = __half22float2(h2v[(size_t)si * 64 + lane]);
        acc0.x += w * hv.x; acc0.y += w * hv.y;
    }
    float2 acc;
    acc.x = (acc0.x + acc1.x) + (acc2.x + acc3.x);
    acc.y = (acc0.y + acc1.y) + (acc2.y + acc3.y);
    float2 bv = reinterpret_cast<const float2*>(bias)[lane];
    acc.x = fmaxf(acc.x + bv.x, 0.f);
    acc.y = fmaxf(acc.y + bv.y, 0.f);
    reinterpret_cast<float2*>(out)[(size_t)node * 64 + lane] = acc;
}

// ---------------------------------------------------------------------------
// Pooling: batch is sorted -> per-block running accumulator, flush on change
// ---------------------------------------------------------------------------
__global__ __launch_bounds__(128) void pool_kernel(const float* __restrict__ out2,
                                                   const int* __restrict__ batch,
                                                   float* __restrict__ d_out) {
    int c = threadIdx.x;                 // channel 0..127
    int node0 = blockIdx.x * 128;
    int nodeEnd = node0 + 128; if (nodeEnd > N_NODES) nodeEnd = N_NODES;
    if (node0 >= N_NODES) return;
    int gprev = batch[node0];
    float acc = 0.f;
    for (int node = node0; node < nodeEnd; ++node) {
        int g = batch[node];
        if (g != gprev) {
            if (gprev >= 0 && gprev < N_GRAPHS) atomicAdd(&d_out[gprev * 128 + c], acc);
            acc = 0.f;
            gprev = g;
        }
        acc += out2[(size_t)node * 128 + c];
    }
    if (gprev >= 0 && gprev < N_GRAPHS) atomicAdd(&d_out[gprev * 128 + c], acc);
}

// Graph boundary detection: batch is sorted, so each graph's start index is
// written exactly once (no contended atomics).
__global__ void bounds_kernel(const int* __restrict__ batch, int* __restrict__ gstart) {
    int idx = blockIdx.x * 256 + threadIdx.x;
    if (idx >= N_NODES) return;
    int g = batch[idx];
    if (g < 0) g = 0; if (g >= N_GRAPHS) g = N_GRAPHS - 1;
    if (idx == 0) {
        for (int j = 0; j <= g; ++j) gstart[j] = 0;
    } else {
        int gp = batch[idx - 1];
        if (gp < 0) gp = 0; if (gp >= N_GRAPHS) gp = N_GRAPHS - 1;
        for (int j = gp + 1; j <= g; ++j) gstart[j] = idx;
    }
    if (idx == N_NODES - 1) {
        for (int j = g + 1; j <= N_GRAPHS; ++j) gstart[j] = N_NODES;
    }
}

__global__ void final_kernel(float* __restrict__ d_out, const int* __restrict__ gstart) {
    int idx = blockIdx.x * 256 + threadIdx.x;
    if (idx < N_GRAPHS * 128) {
        int g = idx >> 7;
        float c = (float)(gstart[g + 1] - gstart[g]);
        if (c < 1.f) c = 1.f;
        d_out[idx] = d_out[idx] / c;
    }
}

// ---------------------------------------------------------------------------
extern "C" void kernel_launch(void* const* d_in, const int* in_sizes, int n_in,
                              void* d_out_v, int out_size, void* d_ws, size_t ws_size,
                              hipStream_t stream) {
    const float* x      = (const float*)d_in[0];
    const float* W1     = (const float*)d_in[1];
    const float* att_s1 = (const float*)d_in[2];
    const float* att_d1 = (const float*)d_in[3];
    const float* bias1  = (const float*)d_in[4];
    const float* W2     = (const float*)d_in[5];
    const float* att_s2 = (const float*)d_in[6];
    const float* att_d2 = (const float*)d_in[7];
    const float* bias2  = (const float*)d_in[8];
    const int*   ei     = (const int*)d_in[9];
    const int*   batch  = (const int*)d_in[10];
    float* d_out = (float*)d_out_v;

    // Workspace layout (float units):
    //  [0, 6.4M)        xh fp16 [N,256]      ... later reused as h2h fp16 [N,128]
    //  [6.4M, 12.8M)    h1h fp16 [N,256]     ... later reused as out2 fp32 [N,128]
    //  [12.8M, 19.2M)   out1h fp16 [N,256]
    //  [19.2M, ...)     attention scalars + CSR ints + W transposes
    float* ws = (float*)d_ws;
    _Float16* xh    = (_Float16*)ws;
    _Float16* h1h   = (_Float16*)(ws + 6400000);
    _Float16* out1h = (_Float16*)(ws + 12800000);
    _Float16* h2h   = (_Float16*)ws;            // xh dead after GEMM1... (GEMM2 writes here)
    float*    out2  = ws + 6400000;             // h1h dead after edge1/att1
    float* a_src1 = ws + 19200000;              // N*4
    float* a_dst1 = a_src1 + 200000;            // N*4
    float* a_src2 = a_dst1 + 200000;            // N
    float* a_dst2 = a_src2 + 50000;             // N
    int* hist     = (int*)(a_dst2 + 50000);     // N
    int* row_ptr  = hist + 50000;               // N+1 (padded to 50016)
    int* row_fill = row_ptr + 50016;            // N (padded to 50016)
    int* ssrc     = row_fill + 50016;           // E_TOT
    int* gstart   = ssrc + E_TOT;               // N_GRAPHS+1 (pad 128)
    int* blockSums    = gstart + 128;           // SCAN_BLOCKS
    int* blockOffsets = blockSums + SCAN_BLOCKS;     // SCAN_BLOCKS+1 (pad 256)
    _Float16* W1t = (_Float16*)(blockOffsets + 256); // 65536 halfs [256][256]
    _Float16* W2t = W1t + 65536;                     // 32768 halfs [128][256]

    // Zero what must be zero
    hipMemsetAsync(hist, 0, N_NODES * sizeof(int), stream);
    hipMemsetAsync(d_out, 0, N_GRAPHS * 128 * sizeof(float), stream);

    // Precision prep
    cast_x_kernel<<<(3200000 + 255) / 256, 256, 0, stream>>>(x, xh, 3200000);
    transpose_w_kernel<<<(65536 + 255) / 256, 256, 0, stream>>>(W1, W1t, 65536, 256);
    transpose_w_kernel<<<(32768 + 255) / 256, 256, 0, stream>>>(W2, W2t, 32768, 128);

    // CSR build
    hist_kernel<<<(E_TOT + 255) / 256, 256, 0, stream>>>(ei, hist);
    scan_phase1<<<SCAN_BLOCKS, 256, 0, stream>>>(hist, blockSums);
    scan_phase2<<<1, 256, 0, stream>>>(blockSums, blockOffsets);
    scan_phase3<<<SCAN_BLOCKS, 256, 0, stream>>>(hist, blockOffsets, row_ptr, row_fill);
    scatter_kernel<<<(E_TOT + 255) / 256, 256, 0, stream>>>(ei, row_fill, ssrc);
    bounds_kernel<<<(N_NODES + 255) / 256, 256, 0, stream>>>(batch, gstart);

    // Layer 1: h1 = x @ W1 (MFMA fp16, fp32 accum)
    {
        dim3 g((N_NODES + 127) / 128, H1C / 128);
        gemm_mfma_kernel<<<g, 256, 0, stream>>>(xh, W1t, h1h, N_NODES, H1C);
    }
    att1_kernel<<<N_NODES / 4, 256, 0, stream>>>((const __half*)h1h, att_s1, att_d1, a_src1, a_dst1);
    edge1_kernel<<<N_NODES / 4, 256, 0, stream>>>(row_ptr, ssrc, (const __half*)h1h,
                                                  a_src1, a_dst1, bias1, (__half*)out1h);

    // Layer 2: h2 = out1 @ W2 (MFMA fp16)
    {
        dim3 g((N_NODES + 127) / 128, OUT_C / 128);
        gemm_mfma_kernel<<<g, 256, 0, stream>>>(out1h, W2t, h2h, N_NODES, OUT_C);
    }
    att2_kernel<<<N_NODES / 4, 256, 0, stream>>>((const __half*)h2h, att_s2, att_d2, a_src2, a_dst2);
    edge2_kernel<<<N_NODES / 4, 256, 0, stream>>>(row_ptr, ssrc, (const __half*)h2h,
                                                  a_src2, a_dst2, bias2, out2);

    // Pooling
    pool_kernel<<<(N_NODES + 127) / 128, 128, 0, stream>>>(out2, batch, d_out);
    final_kernel<<<(N_GRAPHS * 128 + 255) / 256, 256, 0, stream>>>(d_out, gstart);
}